// Round 7
// baseline (325.780 us; speedup 1.0000x reference)
//
#include <hip/hip_runtime.h>
#include <hip/hip_bf16.h>

constexpr int FDIM = 128;

typedef __attribute__((ext_vector_type(8))) short bf16x8;   // 8 bf16 = 4 VGPRs
typedef __attribute__((ext_vector_type(4))) float f32x4;

static __device__ __forceinline__ ushort f2bf(float f){
    union { float f; unsigned u; } v; v.f = f;
    unsigned r = v.u + 0x7fffu + ((v.u >> 16) & 1u);   // RNE
    return (ushort)(r >> 16);
}
static __device__ __forceinline__ float bfhi(unsigned u){
    union { unsigned u; float f; } c; c.u = u & 0xffff0000u; return c.f;
}
static __device__ __forceinline__ float bflo(unsigned u){
    union { unsigned u; float f; } c; c.u = u << 16; return c.f;
}

// ---------------- CSR build (all edge passes dst-windowed: atomics stay in one XCD's L2) ----------------

__global__ __launch_bounds__(256) void k_degree_win(const int* __restrict__ dst, int* __restrict__ deg,
                                                    int E, int WINW){
    const int win   = blockIdx.x & 7;
    const int slice = blockIdx.x >> 3;           // 64 slices
    const int lo = win * WINW, hi = lo + WINW;
    const int ES = (E + 63) >> 6;
    const int e0 = slice * ES, e1 = min(E, e0 + ES);
    for (int e = e0 + (int)threadIdx.x; e < e1; e += 256){
        int d = dst[e];
        if (d >= lo && d < hi) atomicAdd(&deg[d], 1);
    }
}

__global__ __launch_bounds__(256) void k_scan1(const int* __restrict__ deg, int* __restrict__ partial,
                                               int* __restrict__ bsum, int N){
    __shared__ int s[256];
    int i = blockIdx.x*256 + threadIdx.x;
    int v = (i < N) ? deg[i] : 0;
    s[threadIdx.x] = v;
    __syncthreads();
    for (int ofs = 1; ofs < 256; ofs <<= 1){
        int add = (threadIdx.x >= ofs) ? s[threadIdx.x - ofs] : 0;
        __syncthreads();
        s[threadIdx.x] += add;
        __syncthreads();
    }
    if (i < N) partial[i] = s[threadIdx.x];
    if (threadIdx.x == 255) bsum[blockIdx.x] = s[255];
}

__global__ __launch_bounds__(256) void k_scan2(int* __restrict__ bsum, int nb){
    __shared__ int s[256];
    int t = threadIdx.x;
    int v = (t < nb) ? bsum[t] : 0;
    s[t] = v;
    __syncthreads();
    for (int ofs = 1; ofs < 256; ofs <<= 1){
        int add = (t >= ofs) ? s[t - ofs] : 0;
        __syncthreads();
        s[t] += add;
        __syncthreads();
    }
    if (t < nb) bsum[t] = s[t] - v;   // exclusive
}

__global__ __launch_bounds__(256) void k_scan3(const int* __restrict__ partial, const int* __restrict__ deg,
                                               const int* __restrict__ bsum, int* __restrict__ off,
                                               int* __restrict__ cursor, int N){
    int i = blockIdx.x*256 + threadIdx.x;
    if (i < N){
        int o = partial[i] - deg[i] + bsum[blockIdx.x];
        off[i] = o;
        cursor[i] = o;
    }
}

// windowed fill with in-window cursor atomics (csr segment order = arrival order; mean unaffected)
__global__ __launch_bounds__(256) void k_fill_win(const int* __restrict__ src, const int* __restrict__ dst,
                                                  int* __restrict__ cursor, int* __restrict__ csr,
                                                  int E, int WINW){
    const int win   = blockIdx.x & 7;
    const int slice = blockIdx.x >> 3;
    const int lo = win * WINW, hi = lo + WINW;
    const int ES = (E + 63) >> 6;
    const int e0 = slice * ES, e1 = min(E, e0 + ES);
    for (int e = e0 + (int)threadIdx.x; e < e1; e += 256){
        int d = dst[e];
        if (d >= lo && d < hi){
            int p = atomicAdd(&cursor[d], 1);
            csr[p] = src[e];
        }
    }
}

// ---------------- fp32 -> bf16 casts ----------------

__global__ __launch_bounds__(256) void k_cast_bf16(const float* __restrict__ src, ushort* __restrict__ dst, int n){
    int i4 = (blockIdx.x*256 + threadIdx.x) * 4;
    if (i4 < n){
        float4 v = *(const float4*)(src + i4);
        ushort4 o; o.x=f2bf(v.x); o.y=f2bf(v.y); o.z=f2bf(v.z); o.w=f2bf(v.w);
        *(ushort4*)(dst + i4) = o;
    }
}

__global__ __launch_bounds__(256) void k_build_w3(
    const float* __restrict__ W1_l, const float* __restrict__ W1_r,
    const float* __restrict__ Wl1,
    const float* __restrict__ W2_l, const float* __restrict__ W2_r,
    ushort* __restrict__ Wb1, ushort* __restrict__ Wbm, ushort* __restrict__ Wb2)
{
    int i = blockIdx.x*256 + threadIdx.x;   // grid = 320 blocks
    int row = i >> 8, k = i & 255;
    float v; ushort* d;
    if (row < 128){
        int n = row;
        v = (k < 128) ? W1_l[(size_t)n*128 + k] : W1_r[(size_t)n*128 + k - 128];
        d = Wb1 + (size_t)n*256 + k;
    } else if (row < 256){
        int n = row - 128;
        v = Wl1[(size_t)n*256 + k];
        d = Wbm + (size_t)n*256 + k;
    } else {
        int n = row - 256;
        v = (k < 128) ? W2_l[(size_t)n*128 + k] : W2_r[(size_t)n*128 + k - 128];
        d = Wb2 + (size_t)n*256 + k;
    }
    *d = f2bf(v);
}

// ---------------- mean aggregation: one wave per node, 16 edges in flight ----------------

__global__ __launch_bounds__(256) void k_aggregate_bf16(
    const ushort* __restrict__ feat, const int* __restrict__ csr,
    const int* __restrict__ off, const int* __restrict__ deg,
    ushort* __restrict__ agg, int N)
{
    int node = (blockIdx.x*256 + threadIdx.x) >> 6;
    int lane = threadIdx.x & 63;
    if (node >= N) return;
    const int grp = lane >> 4;
    const int sub = lane & 15;
    int o = off[node], d = deg[node];

    float a0=0.f,a1=0.f,a2=0.f,a3=0.f,a4=0.f,a5=0.f,a6=0.f,a7=0.f;

    auto accum = [&](uint4 r){
        a0 += bflo(r.x); a1 += bfhi(r.x);
        a2 += bflo(r.y); a3 += bfhi(r.y);
        a4 += bflo(r.z); a5 += bfhi(r.z);
        a6 += bflo(r.w); a7 += bfhi(r.w);
    };

    for (int base = 0; base < d; base += 64){
        int cnt = min(64, d - base);
        int idx = (lane < cnt) ? csr[o + base + lane] : -1;
        int iters = (cnt + 3) >> 2;
        int j = 0;
        for (; j + 4 <= iters; j += 4){
            int s0 = __shfl(idx, (j+0)*4 + grp);
            int s1 = __shfl(idx, (j+1)*4 + grp);
            int s2 = __shfl(idx, (j+2)*4 + grp);
            int s3 = __shfl(idx, (j+3)*4 + grp);
            unsigned m0 = (s0 >= 0) ? 0xffffffffu : 0u;  int p0 = (s0 >= 0) ? s0 : 0;
            unsigned m1 = (s1 >= 0) ? 0xffffffffu : 0u;  int p1 = (s1 >= 0) ? s1 : 0;
            unsigned m2 = (s2 >= 0) ? 0xffffffffu : 0u;  int p2 = (s2 >= 0) ? s2 : 0;
            unsigned m3 = (s3 >= 0) ? 0xffffffffu : 0u;  int p3 = (s3 >= 0) ? s3 : 0;
            uint4 r0 = *(const uint4*)(feat + (size_t)p0*FDIM + sub*8);
            uint4 r1 = *(const uint4*)(feat + (size_t)p1*FDIM + sub*8);
            uint4 r2 = *(const uint4*)(feat + (size_t)p2*FDIM + sub*8);
            uint4 r3 = *(const uint4*)(feat + (size_t)p3*FDIM + sub*8);
            r0.x &= m0; r0.y &= m0; r0.z &= m0; r0.w &= m0;
            r1.x &= m1; r1.y &= m1; r1.z &= m1; r1.w &= m1;
            r2.x &= m2; r2.y &= m2; r2.z &= m2; r2.w &= m2;
            r3.x &= m3; r3.y &= m3; r3.z &= m3; r3.w &= m3;
            accum(r0); accum(r1); accum(r2); accum(r3);
        }
        for (; j < iters; j++){
            int s = __shfl(idx, j*4 + grp);
            unsigned msk = (s >= 0) ? 0xffffffffu : 0u;
            int sr = (s >= 0) ? s : 0;
            uint4 raw = *(const uint4*)(feat + (size_t)sr*FDIM + sub*8);
            raw.x &= msk; raw.y &= msk; raw.z &= msk; raw.w &= msk;
            accum(raw);
        }
    }

    a0 += __shfl_xor(a0,16); a1 += __shfl_xor(a1,16); a2 += __shfl_xor(a2,16); a3 += __shfl_xor(a3,16);
    a4 += __shfl_xor(a4,16); a5 += __shfl_xor(a5,16); a6 += __shfl_xor(a6,16); a7 += __shfl_xor(a7,16);
    a0 += __shfl_xor(a0,32); a1 += __shfl_xor(a1,32); a2 += __shfl_xor(a2,32); a3 += __shfl_xor(a3,32);
    a4 += __shfl_xor(a4,32); a5 += __shfl_xor(a5,32); a6 += __shfl_xor(a6,32); a7 += __shfl_xor(a7,32);

    if (grp == 0){
        float inv = 1.f / (float)(d > 1 ? d : 1);
        uint4 r;
        r.x = (unsigned)f2bf(a0*inv) | ((unsigned)f2bf(a1*inv) << 16);
        r.y = (unsigned)f2bf(a2*inv) | ((unsigned)f2bf(a3*inv) << 16);
        r.z = (unsigned)f2bf(a4*inv) | ((unsigned)f2bf(a5*inv) << 16);
        r.w = (unsigned)f2bf(a6*inv) | ((unsigned)f2bf(a7*inv) << 16);
        *(uint4*)(agg + (size_t)node*FDIM + sub*8) = r;
    }
}

// ---------------- fused lin1 + mid, register-pipelined ----------------
// A-frags preloaded (8 loads in flight); weights double-buffered across kt (8 loads/stage).
// launch_bounds(256,1): let the allocator keep ~140 VGPRs (R6's 56-VGPR alloc serialized loads).

__global__ __launch_bounds__(256, 1) void k_lin1mid(
    const ushort* __restrict__ aggb, const ushort* __restrict__ xb,
    const ushort* __restrict__ Wb1, const float* __restrict__ b1,
    const ushort* __restrict__ Wbm, const float* __restrict__ bm,
    ushort* __restrict__ hb, int N)
{
    __shared__ __align__(16) ushort S[4][16][136];   // 17.4 KB, wave-private h1
    const int wave = threadIdx.x >> 6, lane = threadIdx.x & 63;
    const int wbase = blockIdx.x*64 + wave*16;
    ushort (*Sw)[136] = S[wave];

    const int m = lane & 15, quad = lane >> 4;
    int r = wbase + m; if (r >= N) r = N - 1;
    const ushort* ap  = aggb + (size_t)r*FDIM + quad*8;
    const ushort* xp  = xb   + (size_t)r*FDIM + quad*8;
    const ushort* w1p = Wb1  + (size_t)m*256 + quad*8;
    const ushort* wmp = Wbm  + (size_t)m*256 + quad*8;

    // preload all A fragments + first weight stage (9 loads in flight)
    bf16x8 agf[4], xf[4];
    #pragma unroll
    for (int c = 0; c < 4; c++) agf[c] = *(const bf16x8*)(ap + c*32);
    #pragma unroll
    for (int c = 0; c < 4; c++) xf[c]  = *(const bf16x8*)(xp + c*32);

    bf16x8 wA[8], wB[8];
    #pragma unroll
    for (int nt = 0; nt < 8; nt++) wA[nt] = *(const bf16x8*)(w1p + (size_t)nt*16*256);

    f32x4 acc[8];
    #pragma unroll
    for (int nt = 0; nt < 8; nt++) acc[nt] = f32x4{0.f,0.f,0.f,0.f};

    #pragma unroll
    for (int kt = 0; kt < 8; kt++){
        bf16x8* cur = (kt & 1) ? wB : wA;
        bf16x8* nxt = (kt & 1) ? wA : wB;
        const ushort* wsrc = (kt < 7) ? w1p : wmp;         // at kt=7, prefetch mid's stage 0
        const int kkn = (kt < 7) ? (kt+1)*32 : 0;
        #pragma unroll
        for (int nt = 0; nt < 8; nt++) nxt[nt] = *(const bf16x8*)(wsrc + (size_t)nt*16*256 + kkn);
        bf16x8 af = (kt < 4) ? agf[kt] : xf[kt-4];
        #pragma unroll
        for (int nt = 0; nt < 8; nt++)
            acc[nt] = __builtin_amdgcn_mfma_f32_16x16x32_bf16(af, cur[nt], acc[nt], 0, 0, 0);
    }

    #pragma unroll
    for (int nt = 0; nt < 8; nt++){
        float b = b1[nt*16 + m];
        acc[nt][0]+=b; acc[nt][1]+=b; acc[nt][2]+=b; acc[nt][3]+=b;
    }
    #pragma unroll
    for (int reg = 0; reg < 4; reg++){
        float ss = 0.f;
        #pragma unroll
        for (int nt = 0; nt < 8; nt++) ss += acc[nt][reg]*acc[nt][reg];
        ss += __shfl_xor(ss,1); ss += __shfl_xor(ss,2); ss += __shfl_xor(ss,4); ss += __shfl_xor(ss,8);
        float invn = 1.f / fmaxf(sqrtf(ss), 1e-12f);
        #pragma unroll
        for (int nt = 0; nt < 8; nt++) acc[nt][reg] = fmaxf(acc[nt][reg]*invn, 0.f);
    }

    // h1 (C-layout) -> LDS [row][col] bf16
    #pragma unroll
    for (int reg = 0; reg < 4; reg++){
        int row = quad*4 + reg;
        #pragma unroll
        for (int nt = 0; nt < 8; nt++) Sw[row][m + nt*16] = f2bf(acc[nt][reg]);
    }
    __syncthreads();

    // mid: [x | h1] @ Wbm^T, relu.  Weight parity continues: mid stage 0 sits in wA (kt=7 prefetch).
    bf16x8 hf[4];
    #pragma unroll
    for (int c = 0; c < 4; c++) hf[c] = *(const bf16x8*)&Sw[m][c*32 + quad*8];

    f32x4 acc2[8];
    #pragma unroll
    for (int nt = 0; nt < 8; nt++) acc2[nt] = f32x4{0.f,0.f,0.f,0.f};

    #pragma unroll
    for (int kt = 0; kt < 8; kt++){
        bf16x8* cur = (kt & 1) ? wB : wA;
        bf16x8* nxt = (kt & 1) ? wA : wB;
        if (kt < 7){
            #pragma unroll
            for (int nt = 0; nt < 8; nt++) nxt[nt] = *(const bf16x8*)(wmp + (size_t)nt*16*256 + (kt+1)*32);
        }
        bf16x8 af = (kt < 4) ? xf[kt] : hf[kt-4];
        #pragma unroll
        for (int nt = 0; nt < 8; nt++)
            acc2[nt] = __builtin_amdgcn_mfma_f32_16x16x32_bf16(af, cur[nt], acc2[nt], 0, 0, 0);
    }

    #pragma unroll
    for (int reg = 0; reg < 4; reg++){
        int row = wbase + quad*4 + reg;
        if (row < N){
            ushort* o = hb + (size_t)row*FDIM + m;
            #pragma unroll
            for (int nt = 0; nt < 8; nt++){
                float v = fmaxf(acc2[nt][reg] + bm[nt*16 + m], 0.f);
                o[nt*16] = f2bf(v);
            }
        }
    }
}

// ---------------- layer-2 linear (NT=4, norm, fp32 out), register-pipelined, 2 row-tiles ----------------

__global__ __launch_bounds__(256, 1) void k_lin2(
    const ushort* __restrict__ aggb, const ushort* __restrict__ hb,
    const ushort* __restrict__ Wb2, const float* __restrict__ b2,
    float* __restrict__ out, int N)
{
    const int lane = threadIdx.x & 63;
    const int wid  = threadIdx.x >> 6;
    const int rowbase = blockIdx.x*128 + wid*32;
    if (rowbase >= N) return;
    const int m = lane & 15, quad = lane >> 4;

    bf16x8 a1f[2][4], a2f[2][4];
    #pragma unroll
    for (int rt = 0; rt < 2; rt++){
        int r = rowbase + rt*16 + m; if (r >= N) r = N - 1;
        const ushort* p1 = aggb + (size_t)r*FDIM + quad*8;
        const ushort* p2 = hb   + (size_t)r*FDIM + quad*8;
        #pragma unroll
        for (int c = 0; c < 4; c++){
            a1f[rt][c] = *(const bf16x8*)(p1 + c*32);
            a2f[rt][c] = *(const bf16x8*)(p2 + c*32);
        }
    }
    const ushort* wp = Wb2 + (size_t)m*256 + quad*8;
    bf16x8 wA[4], wB[4];
    #pragma unroll
    for (int nt = 0; nt < 4; nt++) wA[nt] = *(const bf16x8*)(wp + (size_t)nt*16*256);

    f32x4 acc[2][4];
    #pragma unroll
    for (int rt = 0; rt < 2; rt++)
        #pragma unroll
        for (int nt = 0; nt < 4; nt++) acc[rt][nt] = f32x4{0.f,0.f,0.f,0.f};

    #pragma unroll
    for (int kt = 0; kt < 8; kt++){
        bf16x8* cur = (kt & 1) ? wB : wA;
        bf16x8* nxt = (kt & 1) ? wA : wB;
        if (kt < 7){
            #pragma unroll
            for (int nt = 0; nt < 4; nt++) nxt[nt] = *(const bf16x8*)(wp + (size_t)nt*16*256 + (kt+1)*32);
        }
        #pragma unroll
        for (int rt = 0; rt < 2; rt++){
            bf16x8 af = (kt < 4) ? a1f[rt][kt] : a2f[rt][kt-4];
            #pragma unroll
            for (int nt = 0; nt < 4; nt++)
                acc[rt][nt] = __builtin_amdgcn_mfma_f32_16x16x32_bf16(af, cur[nt], acc[rt][nt], 0, 0, 0);
        }
    }

    #pragma unroll
    for (int rt = 0; rt < 2; rt++){
        #pragma unroll
        for (int nt = 0; nt < 4; nt++){
            float b = b2[nt*16 + m];
            acc[rt][nt][0]+=b; acc[rt][nt][1]+=b; acc[rt][nt][2]+=b; acc[rt][nt][3]+=b;
        }
        #pragma unroll
        for (int reg = 0; reg < 4; reg++){
            float ss = 0.f;
            #pragma unroll
            for (int nt = 0; nt < 4; nt++) ss += acc[rt][nt][reg]*acc[rt][nt][reg];
            ss += __shfl_xor(ss,1); ss += __shfl_xor(ss,2); ss += __shfl_xor(ss,4); ss += __shfl_xor(ss,8);
            float invn = 1.f / fmaxf(sqrtf(ss), 1e-12f);
            int row = rowbase + rt*16 + quad*4 + reg;
            if (row < N){
                float* o = out + (size_t)row*64 + m;
                #pragma unroll
                for (int nt = 0; nt < 4; nt++) o[nt*16] = acc[rt][nt][reg]*invn;
            }
        }
    }
}

// ---------------- launch ----------------

extern "C" void kernel_launch(void* const* d_in, const int* in_sizes, int n_in,
                              void* d_out, int out_size, void* d_ws, size_t ws_size,
                              hipStream_t stream)
{
    const float* x    = (const float*)d_in[0];
    const int*   ei   = (const int*)  d_in[1];
    const float* W1_l = (const float*)d_in[2];
    const float* b1_l = (const float*)d_in[3];
    const float* W1_r = (const float*)d_in[4];
    const float* Wl1  = (const float*)d_in[5];
    const float* bl1  = (const float*)d_in[6];
    const float* W2_l = (const float*)d_in[7];
    const float* b2_l = (const float*)d_in[8];
    const float* W2_r = (const float*)d_in[9];
    float* out = (float*)d_out;

    const int N = in_sizes[0] / FDIM;   // 50000
    const int E = in_sizes[1] / 2;      // 800000

    const int* src = ei;
    const int* dst = ei + E;

    char* p = (char*)d_ws;
    auto carve = [&](size_t bytes) -> void* {
        void* r = (void*)p;
        p += (bytes + 255) & ~(size_t)255;
        return r;
    };
    int*    deg     = (int*)   carve((size_t)N * 4);
    int*    partial = (int*)   carve((size_t)N * 4);
    int*    bsum    = (int*)   carve(256 * 4);
    int*    off     = (int*)   carve((size_t)N * 4);
    int*    cursor  = (int*)   carve((size_t)N * 4);
    int*    csr     = (int*)   carve((size_t)E * 4);
    ushort* xb      = (ushort*)carve((size_t)N * FDIM * 2);
    ushort* hb      = (ushort*)carve((size_t)N * FDIM * 2);
    ushort* aggb    = (ushort*)carve((size_t)N * FDIM * 2);
    ushort* Wb1     = (ushort*)carve((size_t)128 * 256 * 2);
    ushort* Wbm     = (ushort*)carve((size_t)128 * 256 * 2);
    ushort* Wb2     = (ushort*)carve((size_t)64  * 256 * 2);

    hipMemsetAsync(deg, 0, (size_t)N * 4, stream);

    const int gN    = (N + 255) / 256;
    const int gAgg  = (N + 3) / 4;                    // 4 waves/block, 1 node/wave
    const int gF1   = (N + 63) / 64;                  // 4 waves x 16 rows
    const int gL2   = (N + 127) / 128;                // 4 waves x 32 rows
    const int gCast = (N * FDIM / 4 + 255) / 256;
    const int WINW  = (N + 7) / 8;

    // CSR build
    k_degree_win<<<512, 256, 0, stream>>>(dst, deg, E, WINW);
    k_scan1 <<<gN, 256, 0, stream>>>(deg, partial, bsum, N);
    k_scan2 <<<1,  256, 0, stream>>>(bsum, gN);
    k_scan3 <<<gN, 256, 0, stream>>>(partial, deg, bsum, off, cursor, N);
    k_fill_win<<<512, 256, 0, stream>>>(src, dst, cursor, csr, E, WINW);

    // bf16 conversions
    k_cast_bf16<<<gCast, 256, 0, stream>>>(x, xb, N * FDIM);
    k_build_w3<<<320, 256, 0, stream>>>(W1_l, W1_r, Wl1, W2_l, W2_r, Wb1, Wbm, Wb2);

    // layer 1 + mid
    k_aggregate_bf16<<<gAgg, 256, 0, stream>>>(xb, csr, off, deg, aggb, N);
    k_lin1mid<<<gF1, 256, 0, stream>>>(aggb, xb, Wb1, b1_l, Wbm, bl1, hb, N);

    // layer 2
    k_aggregate_bf16<<<gAgg, 256, 0, stream>>>(hb, csr, off, deg, aggb, N);
    k_lin2<<<gL2, 256, 0, stream>>>(aggb, hb, Wb2, b2_l, out, N);
}

// Round 8
// 281.762 us; speedup vs baseline: 1.1562x; 1.1562x over previous
//
#include <hip/hip_runtime.h>
#include <hip/hip_bf16.h>

constexpr int FDIM = 128;

typedef __attribute__((ext_vector_type(8))) short bf16x8;   // 8 bf16 = 4 VGPRs
typedef __attribute__((ext_vector_type(4))) float f32x4;

static __device__ __forceinline__ ushort f2bf(float f){
    union { float f; unsigned u; } v; v.f = f;
    unsigned r = v.u + 0x7fffu + ((v.u >> 16) & 1u);   // RNE
    return (ushort)(r >> 16);
}
static __device__ __forceinline__ float bfhi(unsigned u){
    union { unsigned u; float f; } c; c.u = u & 0xffff0000u; return c.f;
}
static __device__ __forceinline__ float bflo(unsigned u){
    union { unsigned u; float f; } c; c.u = u << 16; return c.f;
}

// ---------------- CSR build (dst-windowed: atomics stay in one XCD's L2) ----------------

__global__ __launch_bounds__(256) void k_degree_win(const int* __restrict__ dst, int* __restrict__ deg,
                                                    int E, int WINW){
    const int win   = blockIdx.x & 7;
    const int slice = blockIdx.x >> 3;           // 64 slices
    const int lo = win * WINW, hi = lo + WINW;
    const int ES = (E + 63) >> 6;
    const int e0 = slice * ES, e1 = min(E, e0 + ES);
    for (int e = e0 + (int)threadIdx.x; e < e1; e += 256){
        int d = dst[e];
        if (d >= lo && d < hi) atomicAdd(&deg[d], 1);
    }
}

__global__ __launch_bounds__(256) void k_scan1(const int* __restrict__ deg, int* __restrict__ partial,
                                               int* __restrict__ bsum, int N){
    __shared__ int s[256];
    int i = blockIdx.x*256 + threadIdx.x;
    int v = (i < N) ? deg[i] : 0;
    s[threadIdx.x] = v;
    __syncthreads();
    for (int ofs = 1; ofs < 256; ofs <<= 1){
        int add = (threadIdx.x >= ofs) ? s[threadIdx.x - ofs] : 0;
        __syncthreads();
        s[threadIdx.x] += add;
        __syncthreads();
    }
    if (i < N) partial[i] = s[threadIdx.x];
    if (threadIdx.x == 255) bsum[blockIdx.x] = s[255];
}

__global__ __launch_bounds__(256) void k_scan2(int* __restrict__ bsum, int nb){
    __shared__ int s[256];
    int t = threadIdx.x;
    int v = (t < nb) ? bsum[t] : 0;
    s[t] = v;
    __syncthreads();
    for (int ofs = 1; ofs < 256; ofs <<= 1){
        int add = (t >= ofs) ? s[t - ofs] : 0;
        __syncthreads();
        s[t] += add;
        __syncthreads();
    }
    if (t < nb) bsum[t] = s[t] - v;   // exclusive
}

__global__ __launch_bounds__(256) void k_scan3(const int* __restrict__ partial, const int* __restrict__ deg,
                                               const int* __restrict__ bsum, int* __restrict__ off,
                                               int* __restrict__ cursor, int N){
    int i = blockIdx.x*256 + threadIdx.x;
    if (i < N){
        int o = partial[i] - deg[i] + bsum[blockIdx.x];
        off[i] = o;
        cursor[i] = o;
    }
}

__global__ __launch_bounds__(256) void k_fill_win(const int* __restrict__ src, const int* __restrict__ dst,
                                                  int* __restrict__ cursor, int* __restrict__ csr,
                                                  int E, int WINW){
    const int win   = blockIdx.x & 7;
    const int slice = blockIdx.x >> 3;
    const int lo = win * WINW, hi = lo + WINW;
    const int ES = (E + 63) >> 6;
    const int e0 = slice * ES, e1 = min(E, e0 + ES);
    for (int e = e0 + (int)threadIdx.x; e < e1; e += 256){
        int d = dst[e];
        if (d >= lo && d < hi){
            int p = atomicAdd(&cursor[d], 1);
            csr[p] = src[e];
        }
    }
}

// ---------------- fp32 -> bf16 cast ----------------

__global__ __launch_bounds__(256) void k_cast_bf16(const float* __restrict__ src, ushort* __restrict__ dst, int n){
    int i4 = (blockIdx.x*256 + threadIdx.x) * 4;
    if (i4 < n){
        float4 v = *(const float4*)(src + i4);
        ushort4 o; o.x=f2bf(v.x); o.y=f2bf(v.y); o.z=f2bf(v.z); o.w=f2bf(v.w);
        *(ushort4*)(dst + i4) = o;
    }
}

// ---------------- weight build: bf16, pre-swizzled into MFMA fragment order ----------------
// Wf[((nt*8+kt)*64 + lane)*8 + j] = W[nt*16 + (lane&15)][kt*32 + (lane>>4)*8 + j]
// => a wave's B-fragment (nt,kt) is 1 KB contiguous: lane reads base + lane*16B (conflict-free).

__global__ __launch_bounds__(256) void k_build_wf(
    const float* __restrict__ W1_l, const float* __restrict__ W1_r,
    const float* __restrict__ Wl1,
    const float* __restrict__ W2_l, const float* __restrict__ W2_r,
    ushort* __restrict__ Wf1, ushort* __restrict__ Wfm, ushort* __restrict__ Wf2)
{
    int i = blockIdx.x*256 + threadIdx.x;   // grid = 320 blocks -> 81920 ushorts
    int f; ushort* dstp; int which;
    if (i < 32768){ f = i;         dstp = Wf1; which = 0; }
    else if (i < 65536){ f = i - 32768; dstp = Wfm; which = 1; }
    else { f = i - 65536; dstp = Wf2; which = 2; }
    int j    = f & 7;
    int lane = (f >> 3) & 63;
    int q    = f >> 9;
    int kt = q & 7, nt = q >> 3;
    int n = nt*16 + (lane & 15);
    int k = kt*32 + (lane >> 4)*8 + j;
    float v;
    if (which == 0)      v = (k < 128) ? W1_l[(size_t)n*128 + k] : W1_r[(size_t)n*128 + (k-128)];
    else if (which == 1) v = Wl1[(size_t)n*256 + k];
    else                 v = (k < 128) ? W2_l[(size_t)n*128 + k] : W2_r[(size_t)n*128 + (k-128)];
    dstp[f] = f2bf(v);
}

// ---------------- mean aggregation: one wave per node, 16 edges in flight ----------------

__global__ __launch_bounds__(256) void k_aggregate_bf16(
    const ushort* __restrict__ feat, const int* __restrict__ csr,
    const int* __restrict__ off, const int* __restrict__ deg,
    ushort* __restrict__ agg, int N)
{
    int node = (blockIdx.x*256 + threadIdx.x) >> 6;
    int lane = threadIdx.x & 63;
    if (node >= N) return;
    const int grp = lane >> 4;
    const int sub = lane & 15;
    int o = off[node], d = deg[node];

    float a0=0.f,a1=0.f,a2=0.f,a3=0.f,a4=0.f,a5=0.f,a6=0.f,a7=0.f;

    auto accum = [&](uint4 r){
        a0 += bflo(r.x); a1 += bfhi(r.x);
        a2 += bflo(r.y); a3 += bfhi(r.y);
        a4 += bflo(r.z); a5 += bfhi(r.z);
        a6 += bflo(r.w); a7 += bfhi(r.w);
    };

    for (int base = 0; base < d; base += 64){
        int cnt = min(64, d - base);
        int idx = (lane < cnt) ? csr[o + base + lane] : -1;
        int iters = (cnt + 3) >> 2;
        int j = 0;
        for (; j + 4 <= iters; j += 4){
            int s0 = __shfl(idx, (j+0)*4 + grp);
            int s1 = __shfl(idx, (j+1)*4 + grp);
            int s2 = __shfl(idx, (j+2)*4 + grp);
            int s3 = __shfl(idx, (j+3)*4 + grp);
            unsigned m0 = (s0 >= 0) ? 0xffffffffu : 0u;  int p0 = (s0 >= 0) ? s0 : 0;
            unsigned m1 = (s1 >= 0) ? 0xffffffffu : 0u;  int p1 = (s1 >= 0) ? s1 : 0;
            unsigned m2 = (s2 >= 0) ? 0xffffffffu : 0u;  int p2 = (s2 >= 0) ? s2 : 0;
            unsigned m3 = (s3 >= 0) ? 0xffffffffu : 0u;  int p3 = (s3 >= 0) ? s3 : 0;
            uint4 r0 = *(const uint4*)(feat + (size_t)p0*FDIM + sub*8);
            uint4 r1 = *(const uint4*)(feat + (size_t)p1*FDIM + sub*8);
            uint4 r2 = *(const uint4*)(feat + (size_t)p2*FDIM + sub*8);
            uint4 r3 = *(const uint4*)(feat + (size_t)p3*FDIM + sub*8);
            r0.x &= m0; r0.y &= m0; r0.z &= m0; r0.w &= m0;
            r1.x &= m1; r1.y &= m1; r1.z &= m1; r1.w &= m1;
            r2.x &= m2; r2.y &= m2; r2.z &= m2; r2.w &= m2;
            r3.x &= m3; r3.y &= m3; r3.z &= m3; r3.w &= m3;
            accum(r0); accum(r1); accum(r2); accum(r3);
        }
        for (; j < iters; j++){
            int s = __shfl(idx, j*4 + grp);
            unsigned msk = (s >= 0) ? 0xffffffffu : 0u;
            int sr = (s >= 0) ? s : 0;
            uint4 raw = *(const uint4*)(feat + (size_t)sr*FDIM + sub*8);
            raw.x &= msk; raw.y &= msk; raw.z &= msk; raw.w &= msk;
            accum(raw);
        }
    }

    a0 += __shfl_xor(a0,16); a1 += __shfl_xor(a1,16); a2 += __shfl_xor(a2,16); a3 += __shfl_xor(a3,16);
    a4 += __shfl_xor(a4,16); a5 += __shfl_xor(a5,16); a6 += __shfl_xor(a6,16); a7 += __shfl_xor(a7,16);
    a0 += __shfl_xor(a0,32); a1 += __shfl_xor(a1,32); a2 += __shfl_xor(a2,32); a3 += __shfl_xor(a3,32);
    a4 += __shfl_xor(a4,32); a5 += __shfl_xor(a5,32); a6 += __shfl_xor(a6,32); a7 += __shfl_xor(a7,32);

    if (grp == 0){
        float inv = 1.f / (float)(d > 1 ? d : 1);
        uint4 r;
        r.x = (unsigned)f2bf(a0*inv) | ((unsigned)f2bf(a1*inv) << 16);
        r.y = (unsigned)f2bf(a2*inv) | ((unsigned)f2bf(a3*inv) << 16);
        r.z = (unsigned)f2bf(a4*inv) | ((unsigned)f2bf(a5*inv) << 16);
        r.w = (unsigned)f2bf(a6*inv) | ((unsigned)f2bf(a7*inv) << 16);
        *(uint4*)(agg + (size_t)node*FDIM + sub*8) = r;
    }
}

// ---------------- LDS-weight linear ----------------
// out[n,:] = post([A1|A2][n,:] @ W^T + bias).  Weights staged once per block into LDS
// (contiguous memcpy of the fragment-ordered Wf), B-frags read via conflict-free ds_read_b128.
// Grid 512 x 4 waves; wave g handles row-tiles g and g+2048, sharing each B-frag read.

template<int NT, bool NORM, bool RELU, bool OUTF32>
__global__ __launch_bounds__(256) void k_lin(
    const ushort* __restrict__ A1, const ushort* __restrict__ A2,
    const ushort* __restrict__ Wf, const float* __restrict__ bias,
    void* __restrict__ outv, int N, int TILES)
{
    __shared__ __align__(16) ushort WS[NT*8*64*8];   // NT*8 KB
    {
        const uint4* wsrc = (const uint4*)Wf;
        uint4* wdst = (uint4*)WS;
        for (int i = threadIdx.x; i < NT*512; i += 256) wdst[i] = wsrc[i];
    }
    __syncthreads();

    const int wave = threadIdx.x >> 6, lane = threadIdx.x & 63;
    const int m = lane & 15, quad = lane >> 4;
    const ushort* WSl = WS + lane*8;    // frag (nt,kt) at WSl + (nt*8+kt)*512

    const int g  = blockIdx.x*4 + wave;          // 0..2047
    const int t0 = g, t1 = g + 2048;
    const bool has2 = (t1 < TILES);

    // A fragments for both tiles up-front (max loads in flight)
    bf16x8 af0[8], af1[8];
    {
        int r0 = min(t0*16 + m, N-1);
        const ushort* p1 = A1 + (size_t)r0*FDIM + quad*8;
        const ushort* p2 = A2 + (size_t)r0*FDIM + quad*8;
        #pragma unroll
        for (int c = 0; c < 4; c++){
            af0[c]   = *(const bf16x8*)(p1 + c*32);
            af0[4+c] = *(const bf16x8*)(p2 + c*32);
        }
    }
    if (has2){
        int r1 = min(t1*16 + m, N-1);
        const ushort* p1 = A1 + (size_t)r1*FDIM + quad*8;
        const ushort* p2 = A2 + (size_t)r1*FDIM + quad*8;
        #pragma unroll
        for (int c = 0; c < 4; c++){
            af1[c]   = *(const bf16x8*)(p1 + c*32);
            af1[4+c] = *(const bf16x8*)(p2 + c*32);
        }
    }

    f32x4 acc0[NT], acc1[NT];
    #pragma unroll
    for (int nt = 0; nt < NT; nt++){ acc0[nt] = f32x4{0.f,0.f,0.f,0.f}; acc1[nt] = f32x4{0.f,0.f,0.f,0.f}; }

    if (has2){
        #pragma unroll
        for (int kt = 0; kt < 8; kt++)
            #pragma unroll
            for (int nt = 0; nt < NT; nt++){
                bf16x8 bfr = *(const bf16x8*)(WSl + (nt*8+kt)*512);
                acc0[nt] = __builtin_amdgcn_mfma_f32_16x16x32_bf16(af0[kt], bfr, acc0[nt], 0, 0, 0);
                acc1[nt] = __builtin_amdgcn_mfma_f32_16x16x32_bf16(af1[kt], bfr, acc1[nt], 0, 0, 0);
            }
    } else {
        #pragma unroll
        for (int kt = 0; kt < 8; kt++)
            #pragma unroll
            for (int nt = 0; nt < NT; nt++){
                bf16x8 bfr = *(const bf16x8*)(WSl + (nt*8+kt)*512);
                acc0[nt] = __builtin_amdgcn_mfma_f32_16x16x32_bf16(af0[kt], bfr, acc0[nt], 0, 0, 0);
            }
    }

    // epilogue per tile
    auto epi = [&](int t, f32x4* acc){
        #pragma unroll
        for (int nt = 0; nt < NT; nt++){
            float b = bias[nt*16 + m];
            acc[nt][0]+=b; acc[nt][1]+=b; acc[nt][2]+=b; acc[nt][3]+=b;
        }
        if (NORM){
            #pragma unroll
            for (int reg = 0; reg < 4; reg++){
                float ss = 0.f;
                #pragma unroll
                for (int nt = 0; nt < NT; nt++) ss += acc[nt][reg]*acc[nt][reg];
                ss += __shfl_xor(ss,1); ss += __shfl_xor(ss,2); ss += __shfl_xor(ss,4); ss += __shfl_xor(ss,8);
                float invn = 1.f / fmaxf(sqrtf(ss), 1e-12f);
                #pragma unroll
                for (int nt = 0; nt < NT; nt++) acc[nt][reg] *= invn;
            }
        }
        if (RELU){
            #pragma unroll
            for (int nt = 0; nt < NT; nt++){
                acc[nt][0]=fmaxf(acc[nt][0],0.f); acc[nt][1]=fmaxf(acc[nt][1],0.f);
                acc[nt][2]=fmaxf(acc[nt][2],0.f); acc[nt][3]=fmaxf(acc[nt][3],0.f);
            }
        }
        #pragma unroll
        for (int reg = 0; reg < 4; reg++){
            int row = t*16 + quad*4 + reg;
            if (row < N){
                if (OUTF32){
                    float* o = (float*)outv + (size_t)row*(NT*16) + m;
                    #pragma unroll
                    for (int nt = 0; nt < NT; nt++) o[nt*16] = acc[nt][reg];
                } else {
                    ushort* o = (ushort*)outv + (size_t)row*(NT*16) + m;
                    #pragma unroll
                    for (int nt = 0; nt < NT; nt++) o[nt*16] = f2bf(acc[nt][reg]);
                }
            }
        }
    };
    epi(t0, acc0);
    if (has2) epi(t1, acc1);
}

// ---------------- launch ----------------

extern "C" void kernel_launch(void* const* d_in, const int* in_sizes, int n_in,
                              void* d_out, int out_size, void* d_ws, size_t ws_size,
                              hipStream_t stream)
{
    const float* x    = (const float*)d_in[0];
    const int*   ei   = (const int*)  d_in[1];
    const float* W1_l = (const float*)d_in[2];
    const float* b1_l = (const float*)d_in[3];
    const float* W1_r = (const float*)d_in[4];
    const float* Wl1  = (const float*)d_in[5];
    const float* bl1  = (const float*)d_in[6];
    const float* W2_l = (const float*)d_in[7];
    const float* b2_l = (const float*)d_in[8];
    const float* W2_r = (const float*)d_in[9];
    float* out = (float*)d_out;

    const int N = in_sizes[0] / FDIM;   // 50000
    const int E = in_sizes[1] / 2;      // 800000

    const int* src = ei;
    const int* dst = ei + E;

    char* p = (char*)d_ws;
    auto carve = [&](size_t bytes) -> void* {
        void* r = (void*)p;
        p += (bytes + 255) & ~(size_t)255;
        return r;
    };
    int*    deg     = (int*)   carve((size_t)N * 4);
    int*    partial = (int*)   carve((size_t)N * 4);
    int*    bsum    = (int*)   carve(256 * 4);
    int*    off     = (int*)   carve((size_t)N * 4);
    int*    cursor  = (int*)   carve((size_t)N * 4);
    int*    csr     = (int*)   carve((size_t)E * 4);
    ushort* xb      = (ushort*)carve((size_t)N * FDIM * 2);
    ushort* h1b     = (ushort*)carve((size_t)N * FDIM * 2);
    ushort* hb      = (ushort*)carve((size_t)N * FDIM * 2);
    ushort* aggb    = (ushort*)carve((size_t)N * FDIM * 2);
    ushort* Wf1     = (ushort*)carve((size_t)32768 * 2);
    ushort* Wfm     = (ushort*)carve((size_t)32768 * 2);
    ushort* Wf2     = (ushort*)carve((size_t)16384 * 2);

    hipMemsetAsync(deg, 0, (size_t)N * 4, stream);

    const int gN    = (N + 255) / 256;
    const int gAgg  = (N + 3) / 4;                    // 4 waves/block, 1 node/wave
    const int gCast = (N * FDIM / 4 + 255) / 256;
    const int WINW  = (N + 7) / 8;
    const int TILES = (N + 15) / 16;                  // 3125
    const int gLin  = 512;                            // 2048 wave slots, 2 tiles/wave

    // CSR build
    k_degree_win<<<512, 256, 0, stream>>>(dst, deg, E, WINW);
    k_scan1 <<<gN, 256, 0, stream>>>(deg, partial, bsum, N);
    k_scan2 <<<1,  256, 0, stream>>>(bsum, gN);
    k_scan3 <<<gN, 256, 0, stream>>>(partial, deg, bsum, off, cursor, N);
    k_fill_win<<<512, 256, 0, stream>>>(src, dst, cursor, csr, E, WINW);

    // bf16 conversions (weights pre-swizzled to fragment order)
    k_cast_bf16<<<gCast, 256, 0, stream>>>(x, xb, N * FDIM);
    k_build_wf<<<320, 256, 0, stream>>>(W1_l, W1_r, Wl1, W2_l, W2_r, Wf1, Wfm, Wf2);

    // layer 1: h1 = relu(norm([agg(x)|x] @ W1^T + b1))
    k_aggregate_bf16<<<gAgg, 256, 0, stream>>>(xb, csr, off, deg, aggb, N);
    k_lin<8, true,  true,  false><<<gLin, 256, 0, stream>>>(aggb, xb, Wf1, b1_l, h1b, N, TILES);

    // mid: h = relu([x|h1] @ Wl1^T + bl1)
    k_lin<8, false, true,  false><<<gLin, 256, 0, stream>>>(xb, h1b, Wfm, bl1, hb, N, TILES);

    // layer 2: out = norm([agg(h)|h] @ W2^T + b2)  (fp32 out)
    k_aggregate_bf16<<<gAgg, 256, 0, stream>>>(hb, csr, off, deg, aggb, N);
    k_lin<4, true,  false, true ><<<gLin, 256, 0, stream>>>(aggb, hb, Wf2, b2_l, out, N, TILES);
}

// Round 9
// 260.978 us; speedup vs baseline: 1.2483x; 1.0796x over previous
//
#include <hip/hip_runtime.h>
#include <hip/hip_bf16.h>

constexpr int FDIM = 128;

typedef __attribute__((ext_vector_type(8))) short bf16x8;   // 8 bf16 = 4 VGPRs
typedef __attribute__((ext_vector_type(4))) float f32x4;

static __device__ __forceinline__ ushort f2bf(float f){
    union { float f; unsigned u; } v; v.f = f;
    unsigned r = v.u + 0x7fffu + ((v.u >> 16) & 1u);   // RNE
    return (ushort)(r >> 16);
}
static __device__ __forceinline__ float bfhi(unsigned u){
    union { unsigned u; float f; } c; c.u = u & 0xffff0000u; return c.f;
}
static __device__ __forceinline__ float bflo(unsigned u){
    union { unsigned u; float f; } c; c.u = u << 16; return c.f;
}

// ---------------- fused degree+rank (1 pass, atomic returns rank) + fp32->bf16 cast ----------------
// Block-range split: first gE blocks do degree/rank, rest do the x cast (independent work,
// overlaps latency-bound atomics with streaming loads).

__global__ __launch_bounds__(256) void k_degcast(
    const int* __restrict__ dst, int* __restrict__ deg, int* __restrict__ rank, int E, int gE,
    const float* __restrict__ xsrc, ushort* __restrict__ xdst, int nx)
{
    if ((int)blockIdx.x < gE){
        int e = blockIdx.x*256 + threadIdx.x;
        if (e < E) rank[e] = atomicAdd(&deg[dst[e]], 1);
    } else {
        int i4 = ((blockIdx.x - gE)*256 + threadIdx.x) * 4;
        if (i4 < nx){
            float4 v = *(const float4*)(xsrc + i4);
            ushort4 o; o.x=f2bf(v.x); o.y=f2bf(v.y); o.z=f2bf(v.z); o.w=f2bf(v.w);
            *(ushort4*)(xdst + i4) = o;
        }
    }
}

__global__ __launch_bounds__(256) void k_scan1(const int* __restrict__ deg, int* __restrict__ partial,
                                               int* __restrict__ bsum, int N){
    __shared__ int s[256];
    int i = blockIdx.x*256 + threadIdx.x;
    int v = (i < N) ? deg[i] : 0;
    s[threadIdx.x] = v;
    __syncthreads();
    for (int ofs = 1; ofs < 256; ofs <<= 1){
        int add = (threadIdx.x >= ofs) ? s[threadIdx.x - ofs] : 0;
        __syncthreads();
        s[threadIdx.x] += add;
        __syncthreads();
    }
    if (i < N) partial[i] = s[threadIdx.x];
    if (threadIdx.x == 255) bsum[blockIdx.x] = s[255];
}

__global__ __launch_bounds__(256) void k_scan2(int* __restrict__ bsum, int nb){
    __shared__ int s[256];
    int t = threadIdx.x;
    int v = (t < nb) ? bsum[t] : 0;
    s[t] = v;
    __syncthreads();
    for (int ofs = 1; ofs < 256; ofs <<= 1){
        int add = (t >= ofs) ? s[t - ofs] : 0;
        __syncthreads();
        s[t] += add;
        __syncthreads();
    }
    if (t < nb) bsum[t] = s[t] - v;   // exclusive
}

__global__ __launch_bounds__(256) void k_scan3(const int* __restrict__ partial, const int* __restrict__ deg,
                                               const int* __restrict__ bsum, int* __restrict__ off, int N){
    int i = blockIdx.x*256 + threadIdx.x;
    if (i < N) off[i] = partial[i] - deg[i] + bsum[blockIdx.x];
}

// rank-based windowed fill: no atomics; 4 dst-windows (~800 KB csr each, L2-resident).
// slot = off[d] + rank[e] is a unique permutation -> correctness independent of ordering.
__global__ __launch_bounds__(256) void k_fill_win(const int* __restrict__ src, const int* __restrict__ dst,
                                                  const int* __restrict__ rank, const int* __restrict__ off,
                                                  int* __restrict__ csr, int E, int WINW){
    const int win   = blockIdx.x & 3;
    const int slice = blockIdx.x >> 2;           // 64 slices
    const int lo = win * WINW, hi = lo + WINW;
    const int ES = (E + 63) >> 6;
    const int e0 = slice * ES, e1 = min(E, e0 + ES);
    for (int e = e0 + (int)threadIdx.x; e < e1; e += 256){
        int d = dst[e];
        if (d >= lo && d < hi)
            csr[off[d] + rank[e]] = src[e];
    }
}

// ---------------- weight build: bf16, pre-swizzled into MFMA fragment order ----------------
// Wf[((nt*8+kt)*64 + lane)*8 + j] = W[nt*16 + (lane&15)][kt*32 + (lane>>4)*8 + j]

__global__ __launch_bounds__(256) void k_build_wf(
    const float* __restrict__ W1_l, const float* __restrict__ W1_r,
    const float* __restrict__ Wl1,
    const float* __restrict__ W2_l, const float* __restrict__ W2_r,
    ushort* __restrict__ Wf1, ushort* __restrict__ Wfm, ushort* __restrict__ Wf2)
{
    int i = blockIdx.x*256 + threadIdx.x;   // grid = 320 blocks -> 81920 ushorts
    int f; ushort* dstp; int which;
    if (i < 32768){ f = i;         dstp = Wf1; which = 0; }
    else if (i < 65536){ f = i - 32768; dstp = Wfm; which = 1; }
    else { f = i - 65536; dstp = Wf2; which = 2; }
    int j    = f & 7;
    int lane = (f >> 3) & 63;
    int q    = f >> 9;
    int kt = q & 7, nt = q >> 3;
    int n = nt*16 + (lane & 15);
    int k = kt*32 + (lane >> 4)*8 + j;
    float v;
    if (which == 0)      v = (k < 128) ? W1_l[(size_t)n*128 + k] : W1_r[(size_t)n*128 + (k-128)];
    else if (which == 1) v = Wl1[(size_t)n*256 + k];
    else                 v = (k < 128) ? W2_l[(size_t)n*128 + k] : W2_r[(size_t)n*128 + (k-128)];
    dstp[f] = f2bf(v);
}

// ---------------- mean aggregation: one wave per node, 16 edges in flight ----------------

__global__ __launch_bounds__(256) void k_aggregate_bf16(
    const ushort* __restrict__ feat, const int* __restrict__ csr,
    const int* __restrict__ off, const int* __restrict__ deg,
    ushort* __restrict__ agg, int N)
{
    int node = (blockIdx.x*256 + threadIdx.x) >> 6;
    int lane = threadIdx.x & 63;
    if (node >= N) return;
    const int grp = lane >> 4;
    const int sub = lane & 15;
    int o = off[node], d = deg[node];

    float a0=0.f,a1=0.f,a2=0.f,a3=0.f,a4=0.f,a5=0.f,a6=0.f,a7=0.f;

    auto accum = [&](uint4 r){
        a0 += bflo(r.x); a1 += bfhi(r.x);
        a2 += bflo(r.y); a3 += bfhi(r.y);
        a4 += bflo(r.z); a5 += bfhi(r.z);
        a6 += bflo(r.w); a7 += bfhi(r.w);
    };

    for (int base = 0; base < d; base += 64){
        int cnt = min(64, d - base);
        int idx = (lane < cnt) ? csr[o + base + lane] : -1;
        int iters = (cnt + 3) >> 2;
        int j = 0;
        for (; j + 4 <= iters; j += 4){
            int s0 = __shfl(idx, (j+0)*4 + grp);
            int s1 = __shfl(idx, (j+1)*4 + grp);
            int s2 = __shfl(idx, (j+2)*4 + grp);
            int s3 = __shfl(idx, (j+3)*4 + grp);
            unsigned m0 = (s0 >= 0) ? 0xffffffffu : 0u;  int p0 = (s0 >= 0) ? s0 : 0;
            unsigned m1 = (s1 >= 0) ? 0xffffffffu : 0u;  int p1 = (s1 >= 0) ? s1 : 0;
            unsigned m2 = (s2 >= 0) ? 0xffffffffu : 0u;  int p2 = (s2 >= 0) ? s2 : 0;
            unsigned m3 = (s3 >= 0) ? 0xffffffffu : 0u;  int p3 = (s3 >= 0) ? s3 : 0;
            uint4 r0 = *(const uint4*)(feat + (size_t)p0*FDIM + sub*8);
            uint4 r1 = *(const uint4*)(feat + (size_t)p1*FDIM + sub*8);
            uint4 r2 = *(const uint4*)(feat + (size_t)p2*FDIM + sub*8);
            uint4 r3 = *(const uint4*)(feat + (size_t)p3*FDIM + sub*8);
            r0.x &= m0; r0.y &= m0; r0.z &= m0; r0.w &= m0;
            r1.x &= m1; r1.y &= m1; r1.z &= m1; r1.w &= m1;
            r2.x &= m2; r2.y &= m2; r2.z &= m2; r2.w &= m2;
            r3.x &= m3; r3.y &= m3; r3.z &= m3; r3.w &= m3;
            accum(r0); accum(r1); accum(r2); accum(r3);
        }
        for (; j < iters; j++){
            int s = __shfl(idx, j*4 + grp);
            unsigned msk = (s >= 0) ? 0xffffffffu : 0u;
            int sr = (s >= 0) ? s : 0;
            uint4 raw = *(const uint4*)(feat + (size_t)sr*FDIM + sub*8);
            raw.x &= msk; raw.y &= msk; raw.z &= msk; raw.w &= msk;
            accum(raw);
        }
    }

    a0 += __shfl_xor(a0,16); a1 += __shfl_xor(a1,16); a2 += __shfl_xor(a2,16); a3 += __shfl_xor(a3,16);
    a4 += __shfl_xor(a4,16); a5 += __shfl_xor(a5,16); a6 += __shfl_xor(a6,16); a7 += __shfl_xor(a7,16);
    a0 += __shfl_xor(a0,32); a1 += __shfl_xor(a1,32); a2 += __shfl_xor(a2,32); a3 += __shfl_xor(a3,32);
    a4 += __shfl_xor(a4,32); a5 += __shfl_xor(a5,32); a6 += __shfl_xor(a6,32); a7 += __shfl_xor(a7,32);

    if (grp == 0){
        float inv = 1.f / (float)(d > 1 ? d : 1);
        uint4 r;
        r.x = (unsigned)f2bf(a0*inv) | ((unsigned)f2bf(a1*inv) << 16);
        r.y = (unsigned)f2bf(a2*inv) | ((unsigned)f2bf(a3*inv) << 16);
        r.z = (unsigned)f2bf(a4*inv) | ((unsigned)f2bf(a5*inv) << 16);
        r.w = (unsigned)f2bf(a6*inv) | ((unsigned)f2bf(a7*inv) << 16);
        *(uint4*)(agg + (size_t)node*FDIM + sub*8) = r;
    }
}

// ---------------- LDS-weight linear ----------------
// Weights staged once per block into LDS (contiguous memcpy of fragment-ordered Wf),
// B-frags via conflict-free ds_read_b128. Grid 512 x 4 waves; 2 row-tiles per wave.

template<int NT, bool NORM, bool RELU, bool OUTF32>
__global__ __launch_bounds__(256) void k_lin(
    const ushort* __restrict__ A1, const ushort* __restrict__ A2,
    const ushort* __restrict__ Wf, const float* __restrict__ bias,
    void* __restrict__ outv, int N, int TILES)
{
    __shared__ __align__(16) ushort WS[NT*8*64*8];   // NT*8 KB
    {
        const uint4* wsrc = (const uint4*)Wf;
        uint4* wdst = (uint4*)WS;
        for (int i = threadIdx.x; i < NT*512; i += 256) wdst[i] = wsrc[i];
    }
    __syncthreads();

    const int wave = threadIdx.x >> 6, lane = threadIdx.x & 63;
    const int m = lane & 15, quad = lane >> 4;
    const ushort* WSl = WS + lane*8;    // frag (nt,kt) at WSl + (nt*8+kt)*512

    const int g  = blockIdx.x*4 + wave;          // 0..2047
    const int t0 = g, t1 = g + 2048;
    const bool has2 = (t1 < TILES);

    bf16x8 af0[8], af1[8];
    {
        int r0 = min(t0*16 + m, N-1);
        const ushort* p1 = A1 + (size_t)r0*FDIM + quad*8;
        const ushort* p2 = A2 + (size_t)r0*FDIM + quad*8;
        #pragma unroll
        for (int c = 0; c < 4; c++){
            af0[c]   = *(const bf16x8*)(p1 + c*32);
            af0[4+c] = *(const bf16x8*)(p2 + c*32);
        }
    }
    if (has2){
        int r1 = min(t1*16 + m, N-1);
        const ushort* p1 = A1 + (size_t)r1*FDIM + quad*8;
        const ushort* p2 = A2 + (size_t)r1*FDIM + quad*8;
        #pragma unroll
        for (int c = 0; c < 4; c++){
            af1[c]   = *(const bf16x8*)(p1 + c*32);
            af1[4+c] = *(const bf16x8*)(p2 + c*32);
        }
    }

    f32x4 acc0[NT], acc1[NT];
    #pragma unroll
    for (int nt = 0; nt < NT; nt++){ acc0[nt] = f32x4{0.f,0.f,0.f,0.f}; acc1[nt] = f32x4{0.f,0.f,0.f,0.f}; }

    if (has2){
        #pragma unroll
        for (int kt = 0; kt < 8; kt++)
            #pragma unroll
            for (int nt = 0; nt < NT; nt++){
                bf16x8 bfr = *(const bf16x8*)(WSl + (nt*8+kt)*512);
                acc0[nt] = __builtin_amdgcn_mfma_f32_16x16x32_bf16(af0[kt], bfr, acc0[nt], 0, 0, 0);
                acc1[nt] = __builtin_amdgcn_mfma_f32_16x16x32_bf16(af1[kt], bfr, acc1[nt], 0, 0, 0);
            }
    } else {
        #pragma unroll
        for (int kt = 0; kt < 8; kt++)
            #pragma unroll
            for (int nt = 0; nt < NT; nt++){
                bf16x8 bfr = *(const bf16x8*)(WSl + (nt*8+kt)*512);
                acc0[nt] = __builtin_amdgcn_mfma_f32_16x16x32_bf16(af0[kt], bfr, acc0[nt], 0, 0, 0);
            }
    }

    auto epi = [&](int t, f32x4* acc){
        #pragma unroll
        for (int nt = 0; nt < NT; nt++){
            float b = bias[nt*16 + m];
            acc[nt][0]+=b; acc[nt][1]+=b; acc[nt][2]+=b; acc[nt][3]+=b;
        }
        if (NORM){
            #pragma unroll
            for (int reg = 0; reg < 4; reg++){
                float ss = 0.f;
                #pragma unroll
                for (int nt = 0; nt < NT; nt++) ss += acc[nt][reg]*acc[nt][reg];
                ss += __shfl_xor(ss,1); ss += __shfl_xor(ss,2); ss += __shfl_xor(ss,4); ss += __shfl_xor(ss,8);
                float invn = 1.f / fmaxf(sqrtf(ss), 1e-12f);
                #pragma unroll
                for (int nt = 0; nt < NT; nt++) acc[nt][reg] *= invn;
            }
        }
        if (RELU){
            #pragma unroll
            for (int nt = 0; nt < NT; nt++){
                acc[nt][0]=fmaxf(acc[nt][0],0.f); acc[nt][1]=fmaxf(acc[nt][1],0.f);
                acc[nt][2]=fmaxf(acc[nt][2],0.f); acc[nt][3]=fmaxf(acc[nt][3],0.f);
            }
        }
        #pragma unroll
        for (int reg = 0; reg < 4; reg++){
            int row = t*16 + quad*4 + reg;
            if (row < N){
                if (OUTF32){
                    float* o = (float*)outv + (size_t)row*(NT*16) + m;
                    #pragma unroll
                    for (int nt = 0; nt < NT; nt++) o[nt*16] = acc[nt][reg];
                } else {
                    ushort* o = (ushort*)outv + (size_t)row*(NT*16) + m;
                    #pragma unroll
                    for (int nt = 0; nt < NT; nt++) o[nt*16] = f2bf(acc[nt][reg]);
                }
            }
        }
    };
    epi(t0, acc0);
    if (has2) epi(t1, acc1);
}

// ---------------- launch ----------------

extern "C" void kernel_launch(void* const* d_in, const int* in_sizes, int n_in,
                              void* d_out, int out_size, void* d_ws, size_t ws_size,
                              hipStream_t stream)
{
    const float* x    = (const float*)d_in[0];
    const int*   ei   = (const int*)  d_in[1];
    const float* W1_l = (const float*)d_in[2];
    const float* b1_l = (const float*)d_in[3];
    const float* W1_r = (const float*)d_in[4];
    const float* Wl1  = (const float*)d_in[5];
    const float* bl1  = (const float*)d_in[6];
    const float* W2_l = (const float*)d_in[7];
    const float* b2_l = (const float*)d_in[8];
    const float* W2_r = (const float*)d_in[9];
    float* out = (float*)d_out;

    const int N = in_sizes[0] / FDIM;   // 50000
    const int E = in_sizes[1] / 2;      // 800000

    const int* src = ei;
    const int* dst = ei + E;

    char* p = (char*)d_ws;
    auto carve = [&](size_t bytes) -> void* {
        void* r = (void*)p;
        p += (bytes + 255) & ~(size_t)255;
        return r;
    };
    int*    deg     = (int*)   carve((size_t)N * 4);
    int*    partial = (int*)   carve((size_t)N * 4);
    int*    bsum    = (int*)   carve(256 * 4);
    int*    off     = (int*)   carve((size_t)N * 4);
    int*    rank    = (int*)   carve((size_t)E * 4);
    int*    csr     = (int*)   carve((size_t)E * 4);
    ushort* xb      = (ushort*)carve((size_t)N * FDIM * 2);
    ushort* h1b     = (ushort*)carve((size_t)N * FDIM * 2);
    ushort* hb      = (ushort*)carve((size_t)N * FDIM * 2);
    ushort* aggb    = (ushort*)carve((size_t)N * FDIM * 2);
    ushort* Wf1     = (ushort*)carve((size_t)32768 * 2);
    ushort* Wfm     = (ushort*)carve((size_t)32768 * 2);
    ushort* Wf2     = (ushort*)carve((size_t)16384 * 2);

    hipMemsetAsync(deg, 0, (size_t)N * 4, stream);

    const int gN    = (N + 255) / 256;
    const int gE    = (E + 255) / 256;
    const int gAgg  = (N + 3) / 4;                    // 4 waves/block, 1 node/wave
    const int gCast = (N * FDIM / 4 + 255) / 256;
    const int WINW  = (N + 3) / 4;                    // 4 windows
    const int TILES = (N + 15) / 16;                  // 3125
    const int gLin  = 512;                            // 2048 wave slots, 2 tiles/wave

    // CSR build + cast (fused first pass)
    k_degcast<<<gE + gCast, 256, 0, stream>>>(dst, deg, rank, E, gE, x, xb, N * FDIM);
    k_scan1 <<<gN, 256, 0, stream>>>(deg, partial, bsum, N);
    k_scan2 <<<1,  256, 0, stream>>>(bsum, gN);
    k_scan3 <<<gN, 256, 0, stream>>>(partial, deg, bsum, off, N);
    k_fill_win<<<256, 256, 0, stream>>>(src, dst, rank, off, csr, E, WINW);

    // weights pre-swizzled to fragment order
    k_build_wf<<<320, 256, 0, stream>>>(W1_l, W1_r, Wl1, W2_l, W2_r, Wf1, Wfm, Wf2);

    // layer 1: h1 = relu(norm([agg(x)|x] @ W1^T + b1))
    k_aggregate_bf16<<<gAgg, 256, 0, stream>>>(xb, csr, off, deg, aggb, N);
    k_lin<8, true,  true,  false><<<gLin, 256, 0, stream>>>(aggb, xb, Wf1, b1_l, h1b, N, TILES);

    // mid: h = relu([x|h1] @ Wl1^T + bl1)
    k_lin<8, false, true,  false><<<gLin, 256, 0, stream>>>(xb, h1b, Wfm, bl1, hb, N, TILES);

    // layer 2: out = norm([agg(h)|h] @ W2^T + b2)  (fp32 out)
    k_aggregate_bf16<<<gAgg, 256, 0, stream>>>(hb, csr, off, deg, aggb, N);
    k_lin<4, true,  false, true ><<<gLin, 256, 0, stream>>>(aggb, hb, Wf2, b2_l, out, N, TILES);
}

// Round 10
// 257.493 us; speedup vs baseline: 1.2652x; 1.0135x over previous
//
#include <hip/hip_runtime.h>
#include <hip/hip_bf16.h>

constexpr int FDIM = 128;

typedef __attribute__((ext_vector_type(8))) short bf16x8;   // 8 bf16 = 4 VGPRs
typedef __attribute__((ext_vector_type(4))) float f32x4;
typedef __attribute__((ext_vector_type(2))) float f32x2;

static __device__ __forceinline__ ushort f2bf(float f){
    union { float f; unsigned u; } v; v.f = f;
    unsigned r = v.u + 0x7fffu + ((v.u >> 16) & 1u);   // RNE
    return (ushort)(r >> 16);
}
static __device__ __forceinline__ unsigned char f2fp8(float f){
    return (unsigned char)(__builtin_amdgcn_cvt_pk_fp8_f32(f, f, 0, false) & 0xff);
}

// ---------------- fused: degree+rank atomics | x cast (bf16 + fp8) | weight swizzle ----------------
// Three independent block ranges in one dispatch (overlaps latency-bound atomics with streaming).

__global__ __launch_bounds__(256) void k_degcast(
    const int* __restrict__ dst, int* __restrict__ deg, int* __restrict__ rank, int E, int gE,
    const float* __restrict__ xsrc, ushort* __restrict__ xb, unsigned char* __restrict__ x8, int nx, int gC,
    const float* __restrict__ W1_l, const float* __restrict__ W1_r,
    const float* __restrict__ Wl1,
    const float* __restrict__ W2_l, const float* __restrict__ W2_r,
    ushort* __restrict__ Wf1, ushort* __restrict__ Wfm, ushort* __restrict__ Wf2)
{
    const int b = (int)blockIdx.x;
    if (b < gE){
        int e = b*256 + threadIdx.x;
        if (e < E) rank[e] = atomicAdd(&deg[dst[e]], 1);
    } else if (b < gE + gC){
        int i4 = ((b - gE)*256 + threadIdx.x) * 4;
        if (i4 < nx){
            float4 v = *(const float4*)(xsrc + i4);
            ushort4 o; o.x=f2bf(v.x); o.y=f2bf(v.y); o.z=f2bf(v.z); o.w=f2bf(v.w);
            *(ushort4*)(xb + i4) = o;
            unsigned w = __builtin_amdgcn_cvt_pk_fp8_f32(v.x, v.y, 0, false);
            w = (unsigned)__builtin_amdgcn_cvt_pk_fp8_f32(v.z, v.w, (int)w, true);
            *(unsigned*)(x8 + i4) = w;
        }
    } else {
        // weight swizzle into MFMA fragment order:
        // Wf[((nt*8+kt)*64 + lane)*8 + j] = W[nt*16 + (lane&15)][kt*32 + (lane>>4)*8 + j]
        int i = (b - gE - gC)*256 + threadIdx.x;       // 320 blocks -> 81920 ushorts
        int f; ushort* dstp; int which;
        if (i < 32768){ f = i;          dstp = Wf1; which = 0; }
        else if (i < 65536){ f = i - 32768; dstp = Wfm; which = 1; }
        else { f = i - 65536; dstp = Wf2; which = 2; }
        int j    = f & 7;
        int lane = (f >> 3) & 63;
        int q    = f >> 9;
        int kt = q & 7, nt = q >> 3;
        int n = nt*16 + (lane & 15);
        int k = kt*32 + (lane >> 4)*8 + j;
        float v;
        if (which == 0)      v = (k < 128) ? W1_l[(size_t)n*128 + k] : W1_r[(size_t)n*128 + (k-128)];
        else if (which == 1) v = Wl1[(size_t)n*256 + k];
        else                 v = (k < 128) ? W2_l[(size_t)n*128 + k] : W2_r[(size_t)n*128 + (k-128)];
        dstp[f] = f2bf(v);
    }
}

__global__ __launch_bounds__(256) void k_scan1(const int* __restrict__ deg, int* __restrict__ partial,
                                               int* __restrict__ bsum, int N){
    __shared__ int s[256];
    int i = blockIdx.x*256 + threadIdx.x;
    int v = (i < N) ? deg[i] : 0;
    s[threadIdx.x] = v;
    __syncthreads();
    for (int ofs = 1; ofs < 256; ofs <<= 1){
        int add = (threadIdx.x >= ofs) ? s[threadIdx.x - ofs] : 0;
        __syncthreads();
        s[threadIdx.x] += add;
        __syncthreads();
    }
    if (i < N) partial[i] = s[threadIdx.x];
    if (threadIdx.x == 255) bsum[blockIdx.x] = s[255];
}

// fused scan2+scan3: every block redundantly scans the <=256 block sums in LDS, then applies.
__global__ __launch_bounds__(256) void k_scan23(const int* __restrict__ partial, const int* __restrict__ deg,
                                                const int* __restrict__ bsum, int* __restrict__ off,
                                                int N, int nb){
    __shared__ int s[256];
    __shared__ int excl;
    int t = threadIdx.x;
    int v = (t < nb) ? bsum[t] : 0;
    s[t] = v;
    __syncthreads();
    for (int ofs = 1; ofs < 256; ofs <<= 1){
        int add = (t >= ofs) ? s[t - ofs] : 0;
        __syncthreads();
        s[t] += add;
        __syncthreads();
    }
    if (t == 0) excl = (blockIdx.x == 0) ? 0 : s[blockIdx.x - 1];
    __syncthreads();
    int i = blockIdx.x*256 + t;
    if (i < N) off[i] = partial[i] - deg[i] + excl;
}

// rank-based windowed fill: no atomics; 4 dst-windows (~800 KB csr each, L2-resident).
__global__ __launch_bounds__(256) void k_fill_win(const int* __restrict__ src, const int* __restrict__ dst,
                                                  const int* __restrict__ rank, const int* __restrict__ off,
                                                  int* __restrict__ csr, int E, int WINW){
    const int win   = blockIdx.x & 3;
    const int slice = blockIdx.x >> 2;           // 64 slices
    const int lo = win * WINW, hi = lo + WINW;
    const int ES = (E + 63) >> 6;
    const int e0 = slice * ES, e1 = min(E, e0 + ES);
    for (int e = e0 + (int)threadIdx.x; e < e1; e += 256){
        int d = dst[e];
        if (d >= lo && d < hi)
            csr[off[d] + rank[e]] = src[e];
    }
}

// ---------------- mean aggregation over fp8 features: one wave per node ----------------
// 4 groups x 16 lanes; group g covers edge 4j+g; lane loads 8 B (8 fp8 cols).
// 4-deep pipeline (16 edges in flight / wave). HW cvt_pk_f32_fp8 decode. Output bf16.

__global__ __launch_bounds__(256) void k_agg8(
    const unsigned char* __restrict__ feat8, const int* __restrict__ csr,
    const int* __restrict__ off, const int* __restrict__ deg,
    ushort* __restrict__ agg, int N)
{
    int node = (blockIdx.x*256 + threadIdx.x) >> 6;
    int lane = threadIdx.x & 63;
    if (node >= N) return;
    const int grp = lane >> 4;
    const int sub = lane & 15;        // cols [sub*8, sub*8+8)
    int o = off[node], d = deg[node];

    float a0=0.f,a1=0.f,a2=0.f,a3=0.f,a4=0.f,a5=0.f,a6=0.f,a7=0.f;

    auto accum = [&](uint2 r){
        f32x2 f;
        f = __builtin_amdgcn_cvt_pk_f32_fp8((int)r.x, false); a0 += f.x; a1 += f.y;
        f = __builtin_amdgcn_cvt_pk_f32_fp8((int)r.x, true);  a2 += f.x; a3 += f.y;
        f = __builtin_amdgcn_cvt_pk_f32_fp8((int)r.y, false); a4 += f.x; a5 += f.y;
        f = __builtin_amdgcn_cvt_pk_f32_fp8((int)r.y, true);  a6 += f.x; a7 += f.y;
    };

    for (int base = 0; base < d; base += 64){
        int cnt = min(64, d - base);
        int idx = (lane < cnt) ? csr[o + base + lane] : -1;
        int iters = (cnt + 3) >> 2;
        int j = 0;
        for (; j + 4 <= iters; j += 4){
            int s0 = __shfl(idx, (j+0)*4 + grp);
            int s1 = __shfl(idx, (j+1)*4 + grp);
            int s2 = __shfl(idx, (j+2)*4 + grp);
            int s3 = __shfl(idx, (j+3)*4 + grp);
            unsigned m0 = (s0 >= 0) ? 0xffffffffu : 0u;  int p0 = (s0 >= 0) ? s0 : 0;
            unsigned m1 = (s1 >= 0) ? 0xffffffffu : 0u;  int p1 = (s1 >= 0) ? s1 : 0;
            unsigned m2 = (s2 >= 0) ? 0xffffffffu : 0u;  int p2 = (s2 >= 0) ? s2 : 0;
            unsigned m3 = (s3 >= 0) ? 0xffffffffu : 0u;  int p3 = (s3 >= 0) ? s3 : 0;
            uint2 r0 = *(const uint2*)(feat8 + (size_t)p0*FDIM + sub*8);
            uint2 r1 = *(const uint2*)(feat8 + (size_t)p1*FDIM + sub*8);
            uint2 r2 = *(const uint2*)(feat8 + (size_t)p2*FDIM + sub*8);
            uint2 r3 = *(const uint2*)(feat8 + (size_t)p3*FDIM + sub*8);
            r0.x &= m0; r0.y &= m0;  r1.x &= m1; r1.y &= m1;   // fp8 0x00 == 0.0
            r2.x &= m2; r2.y &= m2;  r3.x &= m3; r3.y &= m3;
            accum(r0); accum(r1); accum(r2); accum(r3);
        }
        for (; j < iters; j++){
            int s = __shfl(idx, j*4 + grp);
            unsigned msk = (s >= 0) ? 0xffffffffu : 0u;
            int sr = (s >= 0) ? s : 0;
            uint2 raw = *(const uint2*)(feat8 + (size_t)sr*FDIM + sub*8);
            raw.x &= msk; raw.y &= msk;
            accum(raw);
        }
    }

    a0 += __shfl_xor(a0,16); a1 += __shfl_xor(a1,16); a2 += __shfl_xor(a2,16); a3 += __shfl_xor(a3,16);
    a4 += __shfl_xor(a4,16); a5 += __shfl_xor(a5,16); a6 += __shfl_xor(a6,16); a7 += __shfl_xor(a7,16);
    a0 += __shfl_xor(a0,32); a1 += __shfl_xor(a1,32); a2 += __shfl_xor(a2,32); a3 += __shfl_xor(a3,32);
    a4 += __shfl_xor(a4,32); a5 += __shfl_xor(a5,32); a6 += __shfl_xor(a6,32); a7 += __shfl_xor(a7,32);

    if (grp == 0){
        float inv = 1.f / (float)(d > 1 ? d : 1);
        uint4 r;
        r.x = (unsigned)f2bf(a0*inv) | ((unsigned)f2bf(a1*inv) << 16);
        r.y = (unsigned)f2bf(a2*inv) | ((unsigned)f2bf(a3*inv) << 16);
        r.z = (unsigned)f2bf(a4*inv) | ((unsigned)f2bf(a5*inv) << 16);
        r.w = (unsigned)f2bf(a6*inv) | ((unsigned)f2bf(a7*inv) << 16);
        *(uint4*)(agg + (size_t)node*FDIM + sub*8) = r;
    }
}

// ---------------- LDS-weight linear (weights staged once/block, conflict-free ds_read_b128) ----------------
// Grid 512 x 4 waves; 2 row-tiles per wave. FP8OUT additionally emits fp8 copy of the output.

template<int NT, bool NORM, bool RELU, bool OUTF32, bool FP8OUT>
__global__ __launch_bounds__(256) void k_lin(
    const ushort* __restrict__ A1, const ushort* __restrict__ A2,
    const ushort* __restrict__ Wf, const float* __restrict__ bias,
    void* __restrict__ outv, unsigned char* __restrict__ out8, int N, int TILES)
{
    __shared__ __align__(16) ushort WS[NT*8*64*8];   // NT*8 KB
    {
        const uint4* wsrc = (const uint4*)Wf;
        uint4* wdst = (uint4*)WS;
        for (int i = threadIdx.x; i < NT*512; i += 256) wdst[i] = wsrc[i];
    }
    __syncthreads();

    const int wave = threadIdx.x >> 6, lane = threadIdx.x & 63;
    const int m = lane & 15, quad = lane >> 4;
    const ushort* WSl = WS + lane*8;    // frag (nt,kt) at WSl + (nt*8+kt)*512

    const int g  = blockIdx.x*4 + wave;          // 0..2047
    const int t0 = g, t1 = g + 2048;
    const bool has2 = (t1 < TILES);

    bf16x8 af0[8], af1[8];
    {
        int r0 = min(t0*16 + m, N-1);
        const ushort* p1 = A1 + (size_t)r0*FDIM + quad*8;
        const ushort* p2 = A2 + (size_t)r0*FDIM + quad*8;
        #pragma unroll
        for (int c = 0; c < 4; c++){
            af0[c]   = *(const bf16x8*)(p1 + c*32);
            af0[4+c] = *(const bf16x8*)(p2 + c*32);
        }
    }
    if (has2){
        int r1 = min(t1*16 + m, N-1);
        const ushort* p1 = A1 + (size_t)r1*FDIM + quad*8;
        const ushort* p2 = A2 + (size_t)r1*FDIM + quad*8;
        #pragma unroll
        for (int c = 0; c < 4; c++){
            af1[c]   = *(const bf16x8*)(p1 + c*32);
            af1[4+c] = *(const bf16x8*)(p2 + c*32);
        }
    }

    f32x4 acc0[NT], acc1[NT];
    #pragma unroll
    for (int nt = 0; nt < NT; nt++){ acc0[nt] = f32x4{0.f,0.f,0.f,0.f}; acc1[nt] = f32x4{0.f,0.f,0.f,0.f}; }

    if (has2){
        #pragma unroll
        for (int kt = 0; kt < 8; kt++)
            #pragma unroll
            for (int nt = 0; nt < NT; nt++){
                bf16x8 bfr = *(const bf16x8*)(WSl + (nt*8+kt)*512);
                acc0[nt] = __builtin_amdgcn_mfma_f32_16x16x32_bf16(af0[kt], bfr, acc0[nt], 0, 0, 0);
                acc1[nt] = __builtin_amdgcn_mfma_f32_16x16x32_bf16(af1[kt], bfr, acc1[nt], 0, 0, 0);
            }
    } else {
        #pragma unroll
        for (int kt = 0; kt < 8; kt++)
            #pragma unroll
            for (int nt = 0; nt < NT; nt++){
                bf16x8 bfr = *(const bf16x8*)(WSl + (nt*8+kt)*512);
                acc0[nt] = __builtin_amdgcn_mfma_f32_16x16x32_bf16(af0[kt], bfr, acc0[nt], 0, 0, 0);
            }
    }

    auto epi = [&](int t, f32x4* acc){
        #pragma unroll
        for (int nt = 0; nt < NT; nt++){
            float b = bias[nt*16 + m];
            acc[nt][0]+=b; acc[nt][1]+=b; acc[nt][2]+=b; acc[nt][3]+=b;
        }
        if (NORM){
            #pragma unroll
            for (int reg = 0; reg < 4; reg++){
                float ss = 0.f;
                #pragma unroll
                for (int nt = 0; nt < NT; nt++) ss += acc[nt][reg]*acc[nt][reg];
                ss += __shfl_xor(ss,1); ss += __shfl_xor(ss,2); ss += __shfl_xor(ss,4); ss += __shfl_xor(ss,8);
                float invn = 1.f / fmaxf(sqrtf(ss), 1e-12f);
                #pragma unroll
                for (int nt = 0; nt < NT; nt++) acc[nt][reg] *= invn;
            }
        }
        if (RELU){
            #pragma unroll
            for (int nt = 0; nt < NT; nt++){
                acc[nt][0]=fmaxf(acc[nt][0],0.f); acc[nt][1]=fmaxf(acc[nt][1],0.f);
                acc[nt][2]=fmaxf(acc[nt][2],0.f); acc[nt][3]=fmaxf(acc[nt][3],0.f);
            }
        }
        #pragma unroll
        for (int reg = 0; reg < 4; reg++){
            int row = t*16 + quad*4 + reg;
            if (row < N){
                if (OUTF32){
                    float* o = (float*)outv + (size_t)row*(NT*16) + m;
                    #pragma unroll
                    for (int nt = 0; nt < NT; nt++) o[nt*16] = acc[nt][reg];
                } else {
                    ushort* o = (ushort*)outv + (size_t)row*(NT*16) + m;
                    #pragma unroll
                    for (int nt = 0; nt < NT; nt++) o[nt*16] = f2bf(acc[nt][reg]);
                    if (FP8OUT){
                        unsigned char* o8 = out8 + (size_t)row*(NT*16) + m;
                        #pragma unroll
                        for (int nt = 0; nt < NT; nt++) o8[nt*16] = f2fp8(acc[nt][reg]);
                    }
                }
            }
        }
    };
    epi(t0, acc0);
    if (has2) epi(t1, acc1);
}

// ---------------- launch ----------------

extern "C" void kernel_launch(void* const* d_in, const int* in_sizes, int n_in,
                              void* d_out, int out_size, void* d_ws, size_t ws_size,
                              hipStream_t stream)
{
    const float* x    = (const float*)d_in[0];
    const int*   ei   = (const int*)  d_in[1];
    const float* W1_l = (const float*)d_in[2];
    const float* b1_l = (const float*)d_in[3];
    const float* W1_r = (const float*)d_in[4];
    const float* Wl1  = (const float*)d_in[5];
    const float* bl1  = (const float*)d_in[6];
    const float* W2_l = (const float*)d_in[7];
    const float* b2_l = (const float*)d_in[8];
    const float* W2_r = (const float*)d_in[9];
    float* out = (float*)d_out;

    const int N = in_sizes[0] / FDIM;   // 50000
    const int E = in_sizes[1] / 2;      // 800000

    const int* src = ei;
    const int* dst = ei + E;

    char* p = (char*)d_ws;
    auto carve = [&](size_t bytes) -> void* {
        void* r = (void*)p;
        p += (bytes + 255) & ~(size_t)255;
        return r;
    };
    int*           deg     = (int*)   carve((size_t)N * 4);
    int*           partial = (int*)   carve((size_t)N * 4);
    int*           bsum    = (int*)   carve(256 * 4);
    int*           off     = (int*)   carve((size_t)N * 4);
    int*           rank    = (int*)   carve((size_t)E * 4);
    int*           csr     = (int*)   carve((size_t)E * 4);
    ushort*        xb      = (ushort*)carve((size_t)N * FDIM * 2);
    ushort*        h1b     = (ushort*)carve((size_t)N * FDIM * 2);
    ushort*        hb      = (ushort*)carve((size_t)N * FDIM * 2);
    ushort*        aggb    = (ushort*)carve((size_t)N * FDIM * 2);
    unsigned char* x8      = (unsigned char*)carve((size_t)N * FDIM);
    unsigned char* h8      = (unsigned char*)carve((size_t)N * FDIM);
    ushort*        Wf1     = (ushort*)carve((size_t)32768 * 2);
    ushort*        Wfm     = (ushort*)carve((size_t)32768 * 2);
    ushort*        Wf2     = (ushort*)carve((size_t)16384 * 2);

    hipMemsetAsync(deg, 0, (size_t)N * 4, stream);

    const int gN    = (N + 255) / 256;
    const int gE    = (E + 255) / 256;
    const int gAgg  = (N + 3) / 4;                    // 4 waves/block, 1 node/wave
    const int gCast = (N * FDIM / 4 + 255) / 256;
    const int WINW  = (N + 3) / 4;                    // 4 windows
    const int TILES = (N + 15) / 16;                  // 3125
    const int gLin  = 512;                            // 2048 wave slots, 2 tiles/wave

    // pass 1: degree+rank | x->bf16+fp8 | weight swizzle (fused)
    k_degcast<<<gE + gCast + 320, 256, 0, stream>>>(dst, deg, rank, E, gE,
                                                    x, xb, x8, N*FDIM, gCast,
                                                    W1_l, W1_r, Wl1, W2_l, W2_r, Wf1, Wfm, Wf2);
    k_scan1 <<<gN, 256, 0, stream>>>(deg, partial, bsum, N);
    k_scan23<<<gN, 256, 0, stream>>>(partial, deg, bsum, off, N, gN);
    k_fill_win<<<256, 256, 0, stream>>>(src, dst, rank, off, csr, E, WINW);

    // layer 1: h1 = relu(norm([agg(x)|x] @ W1^T + b1))
    k_agg8<<<gAgg, 256, 0, stream>>>(x8, csr, off, deg, aggb, N);
    k_lin<8, true,  true,  false, false><<<gLin, 256, 0, stream>>>(aggb, xb, Wf1, b1_l, h1b, nullptr, N, TILES);

    // mid: h = relu([x|h1] @ Wl1^T + bl1)   (also emits fp8 copy for layer-2 gather)
    k_lin<8, false, true,  false, true ><<<gLin, 256, 0, stream>>>(xb, h1b, Wfm, bl1, hb, h8, N, TILES);

    // layer 2: out = norm([agg(h)|h] @ W2^T + b2)  (fp32 out)
    k_agg8<<<gAgg, 256, 0, stream>>>(h8, csr, off, deg, aggb, N);
    k_lin<4, true,  false, true,  false><<<gLin, 256, 0, stream>>>(aggb, hb, Wf2, b2_l, out, nullptr, N, TILES);
}

// Round 11
// 231.953 us; speedup vs baseline: 1.4045x; 1.1101x over previous
//
#include <hip/hip_runtime.h>
#include <hip/hip_bf16.h>

constexpr int FDIM = 128;

typedef __attribute__((ext_vector_type(8))) short bf16x8;   // 8 bf16 = 4 VGPRs
typedef __attribute__((ext_vector_type(4))) float f32x4;
typedef __attribute__((ext_vector_type(2))) float f32x2;

static __device__ __forceinline__ ushort f2bf(float f){
    union { float f; unsigned u; } v; v.f = f;
    unsigned r = v.u + 0x7fffu + ((v.u >> 16) & 1u);   // RNE
    return (ushort)(r >> 16);
}
static __device__ __forceinline__ unsigned char f2fp8(float f){
    return (unsigned char)(__builtin_amdgcn_cvt_pk_fp8_f32(f, f, 0, false) & 0xff);
}

// ---------------- pass 1 (fused): windowed degree+rank w/ compaction | x cast | weight swizzle ----------------
// Degree blocks: grid (8 windows x 128 slices); deg atomics stay in one XCD's L2 (blockIdx&7 affinity,
// perf heuristic only). Each in-window edge gets rank from the L2-local atomic and is COMPACTED into a
// block-private dense record region (full-line streaming writes; no partial-line rank array).
// NOTE: packs src,dst into 16 bits each — requires N <= 65536 (problem: N=50000).

__global__ __launch_bounds__(256) void k_pass1(
    const int* __restrict__ dst, const int* __restrict__ src,
    int* __restrict__ deg, uint2* __restrict__ recs, int* __restrict__ counts,
    int E, int WINW, int ES, int gW,
    const float* __restrict__ xsrc, ushort* __restrict__ xb, unsigned char* __restrict__ x8, int nx, int gC,
    const float* __restrict__ W1_l, const float* __restrict__ W1_r,
    const float* __restrict__ Wl1,
    const float* __restrict__ W2_l, const float* __restrict__ W2_r,
    ushort* __restrict__ Wf1, ushort* __restrict__ Wfm, ushort* __restrict__ Wf2)
{
    const int b = (int)blockIdx.x;
    if (b < gW){
        __shared__ int lcnt;
        if (threadIdx.x == 0) lcnt = 0;
        __syncthreads();
        const int win = b & 7, slice = b >> 3;
        const int lo = win * WINW, hi = lo + WINW;
        const int e0 = slice * ES, e1 = min(E, e0 + ES);
        uint2* myrec = recs + (size_t)b * ES;
        for (int e = e0 + (int)threadIdx.x; e < e1; e += 256){
            int d = dst[e];
            if (d >= lo && d < hi){
                int r   = atomicAdd(&deg[d], 1);      // XCD-local L2 atomic
                int pos = atomicAdd(&lcnt, 1);        // LDS counter
                myrec[pos] = make_uint2((unsigned)src[e] | ((unsigned)d << 16), (unsigned)r);
            }
        }
        __syncthreads();
        if (threadIdx.x == 0) counts[b] = lcnt;
    } else if (b < gW + gC){
        int i4 = ((b - gW)*256 + threadIdx.x) * 4;
        if (i4 < nx){
            float4 v = *(const float4*)(xsrc + i4);
            ushort4 o; o.x=f2bf(v.x); o.y=f2bf(v.y); o.z=f2bf(v.z); o.w=f2bf(v.w);
            *(ushort4*)(xb + i4) = o;
            unsigned w = __builtin_amdgcn_cvt_pk_fp8_f32(v.x, v.y, 0, false);
            w = (unsigned)__builtin_amdgcn_cvt_pk_fp8_f32(v.z, v.w, (int)w, true);
            *(unsigned*)(x8 + i4) = w;
        }
    } else {
        // weight swizzle into MFMA fragment order:
        // Wf[((nt*8+kt)*64 + lane)*8 + j] = W[nt*16 + (lane&15)][kt*32 + (lane>>4)*8 + j]
        int i = (b - gW - gC)*256 + threadIdx.x;       // 320 blocks -> 81920 ushorts
        int f; ushort* dstp; int which;
        if (i < 32768){ f = i;          dstp = Wf1; which = 0; }
        else if (i < 65536){ f = i - 32768; dstp = Wfm; which = 1; }
        else { f = i - 65536; dstp = Wf2; which = 2; }
        int j    = f & 7;
        int lane = (f >> 3) & 63;
        int q    = f >> 9;
        int kt = q & 7, nt = q >> 3;
        int n = nt*16 + (lane & 15);
        int k = kt*32 + (lane >> 4)*8 + j;
        float v;
        if (which == 0)      v = (k < 128) ? W1_l[(size_t)n*128 + k] : W1_r[(size_t)n*128 + (k-128)];
        else if (which == 1) v = Wl1[(size_t)n*256 + k];
        else                 v = (k < 128) ? W2_l[(size_t)n*128 + k] : W2_r[(size_t)n*128 + (k-128)];
        dstp[f] = f2bf(v);
    }
}

__global__ __launch_bounds__(256) void k_scan1(const int* __restrict__ deg, int* __restrict__ partial,
                                               int* __restrict__ bsum, int N){
    __shared__ int s[256];
    int i = blockIdx.x*256 + threadIdx.x;
    int v = (i < N) ? deg[i] : 0;
    s[threadIdx.x] = v;
    __syncthreads();
    for (int ofs = 1; ofs < 256; ofs <<= 1){
        int add = (threadIdx.x >= ofs) ? s[threadIdx.x - ofs] : 0;
        __syncthreads();
        s[threadIdx.x] += add;
        __syncthreads();
    }
    if (i < N) partial[i] = s[threadIdx.x];
    if (threadIdx.x == 255) bsum[blockIdx.x] = s[255];
}

// fused scan2+scan3: every block redundantly scans the <=256 block sums in LDS, then applies.
__global__ __launch_bounds__(256) void k_scan23(const int* __restrict__ partial, const int* __restrict__ deg,
                                                const int* __restrict__ bsum, int* __restrict__ off,
                                                int N, int nb){
    __shared__ int s[256];
    __shared__ int excl;
    int t = threadIdx.x;
    int v = (t < nb) ? bsum[t] : 0;
    s[t] = v;
    __syncthreads();
    for (int ofs = 1; ofs < 256; ofs <<= 1){
        int add = (t >= ofs) ? s[t - ofs] : 0;
        __syncthreads();
        s[t] += add;
        __syncthreads();
    }
    if (t == 0) excl = (blockIdx.x == 0) ? 0 : s[blockIdx.x - 1];
    __syncthreads();
    int i = blockIdx.x*256 + t;
    if (i < N) off[i] = partial[i] - deg[i] + excl;
}

// ---------------- scatter records -> csr (window-confined ~400 KB, L2-local; coalesced reads) ----------------

__global__ __launch_bounds__(256) void k_scatter(const uint2* __restrict__ recs, const int* __restrict__ counts,
                                                 const int* __restrict__ off, int* __restrict__ csr, int ES){
    const int b = (int)blockIdx.x;
    const int cnt = counts[b];
    const uint2* myrec = recs + (size_t)b * ES;
    for (int i = (int)threadIdx.x; i < cnt; i += 256){
        uint2 rec = myrec[i];
        int d = (int)(rec.x >> 16);
        int s = (int)(rec.x & 0xffffu);
        csr[off[d] + (int)rec.y] = s;
    }
}

// ---------------- mean aggregation over fp8 features: one wave per node, 16 edges in flight ----------------

__global__ __launch_bounds__(256) void k_agg8(
    const unsigned char* __restrict__ feat8, const int* __restrict__ csr,
    const int* __restrict__ off, const int* __restrict__ deg,
    ushort* __restrict__ agg, int N)
{
    int node = (blockIdx.x*256 + threadIdx.x) >> 6;
    int lane = threadIdx.x & 63;
    if (node >= N) return;
    const int grp = lane >> 4;
    const int sub = lane & 15;        // cols [sub*8, sub*8+8)
    int o = off[node], d = deg[node];

    float a0=0.f,a1=0.f,a2=0.f,a3=0.f,a4=0.f,a5=0.f,a6=0.f,a7=0.f;

    auto accum = [&](uint2 r){
        f32x2 f;
        f = __builtin_amdgcn_cvt_pk_f32_fp8((int)r.x, false); a0 += f.x; a1 += f.y;
        f = __builtin_amdgcn_cvt_pk_f32_fp8((int)r.x, true);  a2 += f.x; a3 += f.y;
        f = __builtin_amdgcn_cvt_pk_f32_fp8((int)r.y, false); a4 += f.x; a5 += f.y;
        f = __builtin_amdgcn_cvt_pk_f32_fp8((int)r.y, true);  a6 += f.x; a7 += f.y;
    };

    for (int base = 0; base < d; base += 64){
        int cnt = min(64, d - base);
        int idx = (lane < cnt) ? csr[o + base + lane] : -1;
        int iters = (cnt + 3) >> 2;
        int j = 0;
        for (; j + 4 <= iters; j += 4){
            int s0 = __shfl(idx, (j+0)*4 + grp);
            int s1 = __shfl(idx, (j+1)*4 + grp);
            int s2 = __shfl(idx, (j+2)*4 + grp);
            int s3 = __shfl(idx, (j+3)*4 + grp);
            unsigned m0 = (s0 >= 0) ? 0xffffffffu : 0u;  int p0 = (s0 >= 0) ? s0 : 0;
            unsigned m1 = (s1 >= 0) ? 0xffffffffu : 0u;  int p1 = (s1 >= 0) ? s1 : 0;
            unsigned m2 = (s2 >= 0) ? 0xffffffffu : 0u;  int p2 = (s2 >= 0) ? s2 : 0;
            unsigned m3 = (s3 >= 0) ? 0xffffffffu : 0u;  int p3 = (s3 >= 0) ? s3 : 0;
            uint2 r0 = *(const uint2*)(feat8 + (size_t)p0*FDIM + sub*8);
            uint2 r1 = *(const uint2*)(feat8 + (size_t)p1*FDIM + sub*8);
            uint2 r2 = *(const uint2*)(feat8 + (size_t)p2*FDIM + sub*8);
            uint2 r3 = *(const uint2*)(feat8 + (size_t)p3*FDIM + sub*8);
            r0.x &= m0; r0.y &= m0;  r1.x &= m1; r1.y &= m1;   // fp8 0x00 == 0.0
            r2.x &= m2; r2.y &= m2;  r3.x &= m3; r3.y &= m3;
            accum(r0); accum(r1); accum(r2); accum(r3);
        }
        for (; j < iters; j++){
            int s = __shfl(idx, j*4 + grp);
            unsigned msk = (s >= 0) ? 0xffffffffu : 0u;
            int sr = (s >= 0) ? s : 0;
            uint2 raw = *(const uint2*)(feat8 + (size_t)sr*FDIM + sub*8);
            raw.x &= msk; raw.y &= msk;
            accum(raw);
        }
    }

    a0 += __shfl_xor(a0,16); a1 += __shfl_xor(a1,16); a2 += __shfl_xor(a2,16); a3 += __shfl_xor(a3,16);
    a4 += __shfl_xor(a4,16); a5 += __shfl_xor(a5,16); a6 += __shfl_xor(a6,16); a7 += __shfl_xor(a7,16);
    a0 += __shfl_xor(a0,32); a1 += __shfl_xor(a1,32); a2 += __shfl_xor(a2,32); a3 += __shfl_xor(a3,32);
    a4 += __shfl_xor(a4,32); a5 += __shfl_xor(a5,32); a6 += __shfl_xor(a6,32); a7 += __shfl_xor(a7,32);

    if (grp == 0){
        float inv = 1.f / (float)(d > 1 ? d : 1);
        uint4 r;
        r.x = (unsigned)f2bf(a0*inv) | ((unsigned)f2bf(a1*inv) << 16);
        r.y = (unsigned)f2bf(a2*inv) | ((unsigned)f2bf(a3*inv) << 16);
        r.z = (unsigned)f2bf(a4*inv) | ((unsigned)f2bf(a5*inv) << 16);
        r.w = (unsigned)f2bf(a6*inv) | ((unsigned)f2bf(a7*inv) << 16);
        *(uint4*)(agg + (size_t)node*FDIM + sub*8) = r;
    }
}

// ---------------- LDS-weight linear (weights staged once/block, conflict-free ds_read_b128) ----------------
// Grid 512 x 4 waves; 2 row-tiles per wave. FP8OUT additionally emits fp8 copy of the output.

template<int NT, bool NORM, bool RELU, bool OUTF32, bool FP8OUT>
__global__ __launch_bounds__(256) void k_lin(
    const ushort* __restrict__ A1, const ushort* __restrict__ A2,
    const ushort* __restrict__ Wf, const float* __restrict__ bias,
    void* __restrict__ outv, unsigned char* __restrict__ out8, int N, int TILES)
{
    __shared__ __align__(16) ushort WS[NT*8*64*8];   // NT*8 KB
    {
        const uint4* wsrc = (const uint4*)Wf;
        uint4* wdst = (uint4*)WS;
        for (int i = threadIdx.x; i < NT*512; i += 256) wdst[i] = wsrc[i];
    }
    __syncthreads();

    const int wave = threadIdx.x >> 6, lane = threadIdx.x & 63;
    const int m = lane & 15, quad = lane >> 4;
    const ushort* WSl = WS + lane*8;    // frag (nt,kt) at WSl + (nt*8+kt)*512

    const int g  = blockIdx.x*4 + wave;          // 0..2047
    const int t0 = g, t1 = g + 2048;
    const bool has2 = (t1 < TILES);

    bf16x8 af0[8], af1[8];
    {
        int r0 = min(t0*16 + m, N-1);
        const ushort* p1 = A1 + (size_t)r0*FDIM + quad*8;
        const ushort* p2 = A2 + (size_t)r0*FDIM + quad*8;
        #pragma unroll
        for (int c = 0; c < 4; c++){
            af0[c]   = *(const bf16x8*)(p1 + c*32);
            af0[4+c] = *(const bf16x8*)(p2 + c*32);
        }
    }
    if (has2){
        int r1 = min(t1*16 + m, N-1);
        const ushort* p1 = A1 + (size_t)r1*FDIM + quad*8;
        const ushort* p2 = A2 + (size_t)r1*FDIM + quad*8;
        #pragma unroll
        for (int c = 0; c < 4; c++){
            af1[c]   = *(const bf16x8*)(p1 + c*32);
            af1[4+c] = *(const bf16x8*)(p2 + c*32);
        }
    }

    f32x4 acc0[NT], acc1[NT];
    #pragma unroll
    for (int nt = 0; nt < NT; nt++){ acc0[nt] = f32x4{0.f,0.f,0.f,0.f}; acc1[nt] = f32x4{0.f,0.f,0.f,0.f}; }

    if (has2){
        #pragma unroll
        for (int kt = 0; kt < 8; kt++)
            #pragma unroll
            for (int nt = 0; nt < NT; nt++){
                bf16x8 bfr = *(const bf16x8*)(WSl + (nt*8+kt)*512);
                acc0[nt] = __builtin_amdgcn_mfma_f32_16x16x32_bf16(af0[kt], bfr, acc0[nt], 0, 0, 0);
                acc1[nt] = __builtin_amdgcn_mfma_f32_16x16x32_bf16(af1[kt], bfr, acc1[nt], 0, 0, 0);
            }
    } else {
        #pragma unroll
        for (int kt = 0; kt < 8; kt++)
            #pragma unroll
            for (int nt = 0; nt < NT; nt++){
                bf16x8 bfr = *(const bf16x8*)(WSl + (nt*8+kt)*512);
                acc0[nt] = __builtin_amdgcn_mfma_f32_16x16x32_bf16(af0[kt], bfr, acc0[nt], 0, 0, 0);
            }
    }

    auto epi = [&](int t, f32x4* acc){
        #pragma unroll
        for (int nt = 0; nt < NT; nt++){
            float b = bias[nt*16 + m];
            acc[nt][0]+=b; acc[nt][1]+=b; acc[nt][2]+=b; acc[nt][3]+=b;
        }
        if (NORM){
            #pragma unroll
            for (int reg = 0; reg < 4; reg++){
                float ss = 0.f;
                #pragma unroll
                for (int nt = 0; nt < NT; nt++) ss += acc[nt][reg]*acc[nt][reg];
                ss += __shfl_xor(ss,1); ss += __shfl_xor(ss,2); ss += __shfl_xor(ss,4); ss += __shfl_xor(ss,8);
                float invn = 1.f / fmaxf(sqrtf(ss), 1e-12f);
                #pragma unroll
                for (int nt = 0; nt < NT; nt++) acc[nt][reg] *= invn;
            }
        }
        if (RELU){
            #pragma unroll
            for (int nt = 0; nt < NT; nt++){
                acc[nt][0]=fmaxf(acc[nt][0],0.f); acc[nt][1]=fmaxf(acc[nt][1],0.f);
                acc[nt][2]=fmaxf(acc[nt][2],0.f); acc[nt][3]=fmaxf(acc[nt][3],0.f);
            }
        }
        #pragma unroll
        for (int reg = 0; reg < 4; reg++){
            int row = t*16 + quad*4 + reg;
            if (row < N){
                if (OUTF32){
                    float* o = (float*)outv + (size_t)row*(NT*16) + m;
                    #pragma unroll
                    for (int nt = 0; nt < NT; nt++) o[nt*16] = acc[nt][reg];
                } else {
                    ushort* o = (ushort*)outv + (size_t)row*(NT*16) + m;
                    #pragma unroll
                    for (int nt = 0; nt < NT; nt++) o[nt*16] = f2bf(acc[nt][reg]);
                    if (FP8OUT){
                        unsigned char* o8 = out8 + (size_t)row*(NT*16) + m;
                        #pragma unroll
                        for (int nt = 0; nt < NT; nt++) o8[nt*16] = f2fp8(acc[nt][reg]);
                    }
                }
            }
        }
    };
    epi(t0, acc0);
    if (has2) epi(t1, acc1);
}

// ---------------- launch ----------------

extern "C" void kernel_launch(void* const* d_in, const int* in_sizes, int n_in,
                              void* d_out, int out_size, void* d_ws, size_t ws_size,
                              hipStream_t stream)
{
    const float* x    = (const float*)d_in[0];
    const int*   ei   = (const int*)  d_in[1];
    const float* W1_l = (const float*)d_in[2];
    const float* b1_l = (const float*)d_in[3];
    const float* W1_r = (const float*)d_in[4];
    const float* Wl1  = (const float*)d_in[5];
    const float* bl1  = (const float*)d_in[6];
    const float* W2_l = (const float*)d_in[7];
    const float* b2_l = (const float*)d_in[8];
    const float* W2_r = (const float*)d_in[9];
    float* out = (float*)d_out;

    const int N = in_sizes[0] / FDIM;   // 50000
    const int E = in_sizes[1] / 2;      // 800000

    const int* src = ei;
    const int* dst = ei + E;

    char* p = (char*)d_ws;
    auto carve = [&](size_t bytes) -> void* {
        void* r = (void*)p;
        p += (bytes + 255) & ~(size_t)255;
        return r;
    };
    const int SLICES = 128;
    const int gW     = SLICES * 8;                    // 1024 degree blocks
    const int ES     = (E + SLICES - 1) / SLICES;     // 6250 edges/slice

    int*           deg     = (int*)   carve((size_t)N * 4);
    int*           partial = (int*)   carve((size_t)N * 4);
    int*           bsum    = (int*)   carve(256 * 4);
    int*           off     = (int*)   carve((size_t)N * 4);
    int*           csr     = (int*)   carve((size_t)E * 4);
    uint2*         recs    = (uint2*) carve((size_t)gW * ES * 8);
    int*           counts  = (int*)   carve((size_t)gW * 4);
    ushort*        xb      = (ushort*)carve((size_t)N * FDIM * 2);
    ushort*        h1b     = (ushort*)carve((size_t)N * FDIM * 2);
    ushort*        hb      = (ushort*)carve((size_t)N * FDIM * 2);
    ushort*        aggb    = (ushort*)carve((size_t)N * FDIM * 2);
    unsigned char* x8      = (unsigned char*)carve((size_t)N * FDIM);
    unsigned char* h8      = (unsigned char*)carve((size_t)N * FDIM);
    ushort*        Wf1     = (ushort*)carve((size_t)32768 * 2);
    ushort*        Wfm     = (ushort*)carve((size_t)32768 * 2);
    ushort*        Wf2     = (ushort*)carve((size_t)16384 * 2);

    hipMemsetAsync(deg, 0, (size_t)N * 4, stream);

    const int gN    = (N + 255) / 256;
    const int gAgg  = (N + 3) / 4;                    // 4 waves/block, 1 node/wave
    const int gCast = (N * FDIM / 4 + 255) / 256;
    const int WINW  = (N + 7) / 8;                    // 8 windows
    const int TILES = (N + 15) / 16;                  // 3125
    const int gLin  = 512;                            // 2048 wave slots, 2 tiles/wave

    // pass 1: windowed degree+rank+compact | x->bf16+fp8 | weight swizzle (fused)
    k_pass1<<<gW + gCast + 320, 256, 0, stream>>>(dst, src, deg, recs, counts, E, WINW, ES, gW,
                                                  x, xb, x8, N*FDIM, gCast,
                                                  W1_l, W1_r, Wl1, W2_l, W2_r, Wf1, Wfm, Wf2);
    k_scan1 <<<gN, 256, 0, stream>>>(deg, partial, bsum, N);
    k_scan23<<<gN, 256, 0, stream>>>(partial, deg, bsum, off, N, gN);
    k_scatter<<<gW, 256, 0, stream>>>(recs, counts, off, csr, ES);

    // layer 1: h1 = relu(norm([agg(x)|x] @ W1^T + b1))
    k_agg8<<<gAgg, 256, 0, stream>>>(x8, csr, off, deg, aggb, N);
    k_lin<8, true,  true,  false, false><<<gLin, 256, 0, stream>>>(aggb, xb, Wf1, b1_l, h1b, nullptr, N, TILES);

    // mid: h = relu([x|h1] @ Wl1^T + bl1)   (also emits fp8 copy for layer-2 gather)
    k_lin<8, false, true,  false, true ><<<gLin, 256, 0, stream>>>(xb, h1b, Wfm, bl1, hb, h8, N, TILES);

    // layer 2: out = norm([agg(h)|h] @ W2^T + b2)  (fp32 out)
    k_agg8<<<gAgg, 256, 0, stream>>>(h8, csr, off, deg, aggb, N);
    k_lin<4, true,  false, true,  false><<<gLin, 256, 0, stream>>>(aggb, hb, Wf2, b2_l, out, nullptr, N, TILES);
}